// Round 19
// baseline (420.327 us; speedup 1.0000x reference)
//
#include <hip/hip_runtime.h>
#include <cstdio>

// B=64, CIN=256, CP=128, N=1024. Stacked conv: 384 = theta|phi|gamma.
// r17 WIN: 8-phase template cut K1 140->69us. r18 lesson: mgemm8 on K8's tiny
// GEMM (M=256, K=128) was 127us (MfmaUtil 1.3%, degenerate 1-tile-M geometry
// at 1 block/CU); the 8-phase template only pays on deep-K pipelines. r19:
// K8 reverts to the 2-phase mgemm (1024 blocks, 2/CU) writing out0 in
// [64][256][1024] f32 == x's layout -> final_kernel is a pure elementwise
// stream. K1/K4/K7 stay mgemm8 (K4 single z=64 launch; K7 fuses 1/Z).
// Precision: K-TRIPLED 3-product via k->slot remaps ([Wh|Wl|Wh]·[xh|xh|xl]).
// Softmax: fixed-offset exp(S-40), Z fused in K4 epilogue, 1/Z in K7 scale.

typedef __attribute__((ext_vector_type(4))) float f32x4;
typedef __attribute__((ext_vector_type(8))) short short8;
typedef __attribute__((ext_vector_type(4))) unsigned short u16x4;
typedef __attribute__((ext_vector_type(8))) unsigned short u16x8;
typedef __attribute__((ext_vector_type(4))) int i32x4;

static constexpr float CEXP = 40.0f;
static constexpr float LOG2E = 1.4426950408889634f;

// ---- workspace layout (floats) ----
static constexpr long OFF_WST  = 0;           // u16[384][768] = 147456 fl
static constexpr long OFF_VEC  = 147456;      // 1152: b|g|beta stacked
static constexpr long OFF_R1   = 148608;      // 768  (zeroed region start)
static constexpr long OFF_R2   = 149376;      // 512
static constexpr long OFF_ZS   = 149888;      // 64   (zeroed: 1344 total)
static constexpr long OFF_SC1  = 149952;      // 384
static constexpr long OFF_SH1  = 150336;      // 384
static constexpr long OFF_SC2  = 150720;      // 256
static constexpr long OFF_SH2  = 150976;      // 256
static constexpr long OFF_INVZ = 151232;      // 64
static constexpr long OFF_OM   = 151296;      // u16[256][128] = 16384 fl
static constexpr long OFF_X    = 262144;                // 16777216 fl: xs/tps u16[65536][512]
static constexpr long OFF_Y    = OFF_X + 16777216;      // 33554432 fl: YT f32 [65536][384]
                                                        //   -> P bf16 [64][1024][1024]
                                                        //   -> out0 f32 [64][256][1024]
static constexpr long OFF_C    = OFF_Y + 33554432;      // 4194304 fl: g bf16 [64][128][1024]
static constexpr long OFF_D    = OFF_C + 4194304;       // 4194304 fl: satT bf16 [65536][128]
static constexpr long WS_FLOATS = OFF_D + 4194304;      // 58982400 fl = 225 MiB

__device__ __forceinline__ unsigned short f2bf(float f) {
    union { float f; unsigned u; } x; x.f = f;
    unsigned r = x.u + 0x7FFF + ((x.u >> 16) & 1);
    return (unsigned short)(r >> 16);
}
__device__ __forceinline__ float bf2f(unsigned short h) {
    union { unsigned u; float f; } x; x.u = ((unsigned)h) << 16; return x.f;
}
__device__ __forceinline__ void glds16(const void* g, void* l) {
    __builtin_amdgcn_global_load_lds(
        (const __attribute__((address_space(1))) unsigned int*)g,
        (__attribute__((address_space(3))) unsigned int*)l, 16, 0, 0);
}

// ---------------- utility kernels ----------------
__global__ void zero_n(float* p, int n) {
    int i = blockIdx.x * 256 + threadIdx.x;
    if (i < n) p[i] = 0.f;
}

__global__ void invz_kernel(const float* zs, float* invz) {
    int i = threadIdx.x;
    if (i < 64) invz[i] = 1.0f / zs[i];
}

// stack theta|phi|gamma weights K-tripled [384][768]; omega -> bf16 [256][128]
__global__ void stack_params(const float* tw, const float* tb, const float* tg, const float* tbe,
                             const float* pw, const float* pb, const float* pg, const float* pbe,
                             const float* gw, const float* gb, const float* gg, const float* gbe,
                             const float* ow,
                             unsigned short* Wsp, float* vecs, unsigned short* omB) {
    int i = blockIdx.x * 256 + threadIdx.x;
    if (i < 98304) {
        int o = i >> 8, c = i & 255;
        float v = (o < 128) ? tw[o * 256 + c] : (o < 256) ? pw[(o - 128) * 256 + c]
                                                          : gw[(o - 256) * 256 + c];
        unsigned short hi = f2bf(v);
        unsigned short lo = f2bf(v - bf2f(hi));
        Wsp[(long)o * 768 + c] = hi;
        Wsp[(long)o * 768 + 256 + c] = lo;
        Wsp[(long)o * 768 + 512 + c] = hi;
    }
    if (i < 32768) omB[i] = f2bf(ow[i]);
    if (i < 384) {
        float b  = (i < 128) ? tb[i]  : (i < 256) ? pb[i - 128]  : gb[i - 256];
        float g  = (i < 128) ? tg[i]  : (i < 256) ? pg[i - 128]  : gg[i - 256];
        float be = (i < 128) ? tbe[i] : (i < 256) ? pbe[i - 128] : gbe[i - 256];
        vecs[i] = b; vecs[384 + i] = g; vecs[768 + i] = be;
    }
}

// x [64][256][1024] f32 -> xs [64][1024][512] bf16 rows [xh | xl]
__global__ __launch_bounds__(256) void transpose_x(const float* __restrict__ x,
                                                   unsigned short* __restrict__ xs) {
    __shared__ float t[64][68];
    const int b = blockIdx.z, c0 = blockIdx.y * 64, n0 = blockIdx.x * 64;
    const int tid = threadIdx.x;
#pragma unroll
    for (int p = 0; p < 4; ++p) {
        int i = tid + p * 256;
        int c = i >> 4, n4 = (i & 15) << 2;
        f32x4 v = *(const f32x4*)&x[((long)b * 256 + c0 + c) * 1024 + n0 + n4];
        *(f32x4*)&t[c][n4] = v;
    }
    __syncthreads();
#pragma unroll
    for (int p = 0; p < 4; ++p) {
        int i = tid + p * 256;
        int n = i >> 4, c4 = (i & 15) << 2;
        u16x4 h, l;
#pragma unroll
        for (int j = 0; j < 4; ++j) {
            float v = t[c4 + j][n];
            unsigned short hh = f2bf(v);
            h[j] = hh;
            l[j] = f2bf(v - bf2f(hh));
        }
        long o = ((long)b * 1024 + n0 + n) * 512 + c0 + c4;
        *(u16x4*)&xs[o] = h;
        *(u16x4*)&xs[o + 256] = l;
    }
}

// ================= 8-phase GEMM: BM=256, BN=128, BK=64, 8 waves =================
template <int NT, bool OUT_BF16, bool HAS_RBIAS, bool HAS_CBIAS, bool HAS_SCALE,
          bool CSTAT, bool EXPZ>
__global__ __launch_bounds__(512) void mgemm8(
    int gx, int gy,
    const unsigned short* __restrict__ A, long aBatch, long aOff, int lda,
    int athr, int adlo, int adhi,
    const unsigned short* __restrict__ B, long bBatch, long bOff, int ldb,
    int bthr, int bdlo, int bdhi,
    void* __restrict__ Cq, long cBatch, int ldc,
    const float* __restrict__ bias, const float* __restrict__ bscale,
    float* __restrict__ stats, int statStride, float* __restrict__ zsum) {
    constexpr int AU = 256 * 64;   // u16 (32 KB)
    constexpr int BU = 128 * 64;   // u16 (16 KB)
    constexpr int BUFU = AU + BU;  // 48 KB
    __shared__ unsigned short lds[3 * BUFU];   // 144 KB ring; reused by epilogue

    const int nwg = gridDim.x, bid = blockIdx.x;
    const int wk = ((bid & 7) * (nwg >> 3)) + (bid >> 3);   // nwg % 8 == 0
    const int bx = wk % gx;
    const int byz = wk / gx;
    const int by = byz % gy;
    const int z = byz / gy;

    const int tid = threadIdx.x;
    const int wave = tid >> 6, lane = tid & 63;
    const int wm = wave >> 1, wn = wave & 1;            // 4 x 2 wave grid
    const int lr = lane & 15, lg = lane >> 4;
    const int m0 = by * 256, n0 = bx * 128;
    const long aB = aOff + (long)z * aBatch;
    const long bB = bOff + (long)z * bBatch;
    const int grow = lane >> 3, gq = lane & 7;          // staging lane split

    f32x4 acc[4][4];
#pragma unroll
    for (int i = 0; i < 4; ++i)
#pragma unroll
        for (int j = 0; j < 4; ++j) acc[i][j] = (f32x4){0.f, 0.f, 0.f, 0.f};

    auto stageA = [&](int buf, int kt, int t) {
        const int ka = (kt < athr ? kt + adlo : kt + adhi);
        int seg = wave + t * 8;                 // 32 segs of 8 rows (1 KB each)
        int row = seg * 8 + grow;
        glds16(A + aB + (long)(m0 + row) * lda + ka + ((gq ^ (row & 7)) << 3),
               &lds[buf + seg * 512]);
    };
    auto stageB = [&](int buf, int kt, int t) {
        const int kb = (kt < bthr ? kt + bdlo : kt + bdhi);
        int seg = wave + t * 8;                 // 16 segs
        int row = seg * 8 + grow;
        glds16(B + bB + (long)(n0 + row) * ldb + kb + ((gq ^ (row & 7)) << 3),
               &lds[buf + AU + seg * 512]);
    };
    auto stage_all = [&](int buf, int kt) {
#pragma unroll
        for (int t = 0; t < 4; ++t) stageA(buf, kt, t);
#pragma unroll
        for (int t = 0; t < 2; ++t) stageB(buf, kt, t);
    };

    stage_all(0, 0);
    if (NT > 1) stage_all(BUFU, 64);

#pragma unroll
    for (int t = 0; t < NT; ++t) {
        const unsigned bb = (unsigned)(((t % 3) * BUFU) * 2);   // byte base
        if (t + 1 < NT) asm volatile("s_waitcnt vmcnt(6)" ::: "memory");
        else            asm volatile("s_waitcnt vmcnt(0)" ::: "memory");
        asm volatile("s_barrier" ::: "memory");   // tile t resident for all waves
        const int sbuf = ((t + 2) % 3) * BUFU;
        const int skt = (t + 2) * 64;
#pragma unroll
        for (int p = 0; p < 2; ++p) {
            i32x4 a4[4], b4[4];
#pragma unroll
            for (int mi = 0; mi < 4; ++mi) {
                unsigned r = (unsigned)(wm * 64 + mi * 16 + lr);
                unsigned ad = bb + r * 128 + ((unsigned)(((p << 2) | lg) ^ (r & 7)) << 4);
                asm volatile("ds_read_b128 %0, %1" : "=v"(a4[mi]) : "v"(ad));
            }
#pragma unroll
            for (int ni = 0; ni < 4; ++ni) {
                unsigned r = (unsigned)(wn * 64 + ni * 16 + lr);
                unsigned ad = bb + (unsigned)(AU * 2) + r * 128 +
                              ((unsigned)(((p << 2) | lg) ^ (r & 7)) << 4);
                asm volatile("ds_read_b128 %0, %1" : "=v"(b4[ni]) : "v"(ad));
            }
            if (t + 2 < NT) {           // half of tile t+2's staging per phase
                if (p == 0) { stageA(sbuf, skt, 0); stageA(sbuf, skt, 1); stageA(sbuf, skt, 2); }
                else        { stageA(sbuf, skt, 3); stageB(sbuf, skt, 0); stageB(sbuf, skt, 1); }
            }
            asm volatile("s_waitcnt lgkmcnt(0)" ::: "memory");
            __builtin_amdgcn_sched_barrier(0);
            __builtin_amdgcn_s_setprio(1);
#pragma unroll
            for (int ni = 0; ni < 4; ++ni) {
                short8 bh = __builtin_bit_cast(short8, b4[ni]);
#pragma unroll
                for (int mi = 0; mi < 4; ++mi)
                    acc[mi][ni] = __builtin_amdgcn_mfma_f32_16x16x32_bf16(
                        __builtin_bit_cast(short8, a4[mi]), bh, acc[mi][ni], 0, 0, 0);
            }
            __builtin_amdgcn_s_setprio(0);
            if (p == 0) asm volatile("s_barrier" ::: "memory");
        }
    }

    // ---- transform: acc = acc*scale + row_bias + col_bias ----
    const float sc = HAS_SCALE ? bscale[z] : 1.0f;
#pragma unroll
    for (int mi = 0; mi < 4; ++mi) {
        const int mrow = m0 + wm * 64 + mi * 16 + lg * 4;
        f32x4 rb = (f32x4){0.f, 0.f, 0.f, 0.f};
        if constexpr (HAS_RBIAS) rb = *(const f32x4*)&bias[mrow];
#pragma unroll
        for (int ni = 0; ni < 4; ++ni) {
            float cbv = HAS_CBIAS ? bias[n0 + wn * 64 + ni * 16 + lr] : 0.0f;
            acc[mi][ni] = acc[mi][ni] * sc + rb + (f32x4){cbv, cbv, cbv, cbv};
        }
    }
    if constexpr (CSTAT) {
#pragma unroll
        for (int ni = 0; ni < 4; ++ni) {
            float a = 0.f, b2 = 0.f;
#pragma unroll
            for (int mi = 0; mi < 4; ++mi) {
                f32x4 v = acc[mi][ni];
                a += v[0] + v[1] + v[2] + v[3];
                b2 += v[0] * v[0] + v[1] * v[1] + v[2] * v[2] + v[3] * v[3];
            }
            a += __shfl_xor(a, 16); a += __shfl_xor(a, 32);
            b2 += __shfl_xor(b2, 16); b2 += __shfl_xor(b2, 32);
            if (lg == 0) {
                const int col = n0 + wn * 64 + ni * 16 + lr;
                atomicAdd(&stats[col], a);
                atomicAdd(&stats[statStride + col], b2);
            }
        }
    }

    if constexpr (OUT_BF16) {
        __syncthreads();
        unsigned short* tileH = lds;          // [256][128] bf16 = 64 KB
        float zacc = 0.f;
#pragma unroll
        for (int mi = 0; mi < 4; ++mi) {
            const int lrow = wm * 64 + mi * 16 + lg * 4;
#pragma unroll
            for (int ni = 0; ni < 4; ++ni) {
                const int cl = wn * 64 + ni * 16 + lr;
                f32x4 v = acc[mi][ni];
#pragma unroll
                for (int j = 0; j < 4; ++j) {
                    unsigned short o;
                    if constexpr (EXPZ) {
                        float e = exp2f((v[j] - CEXP) * LOG2E);
                        o = f2bf(e);
                        zacc += bf2f(o);
                    } else {
                        o = f2bf(v[j]);
                    }
                    tileH[(lrow + j) * 128 + cl] = o;
                }
            }
        }
        __syncthreads();
#pragma unroll
        for (int i = tid; i < 256 * 128 / 8; i += 512) {
            int row = i >> 4, c8 = (i & 15) << 3;
            u16x8 vv = *(const u16x8*)&tileH[row * 128 + c8];
            *(u16x8*)&((unsigned short*)Cq)[(long)z * cBatch + (long)(m0 + row) * ldc + n0 + c8] = vv;
        }
        if constexpr (EXPZ) {
            __syncthreads();
            float* red = (float*)lds;
            red[tid] = zacc;
            __syncthreads();
            for (int o = 256; o > 0; o >>= 1) {
                if (tid < o) red[tid] += red[tid + o];
                __syncthreads();
            }
            if (tid == 0) atomicAdd(&zsum[z], red[0]);
        }
    } else {
        // f32 output in two 128-row passes (64 KB tile each)
        float* tileF = (float*)lds;
#pragma unroll
        for (int pass = 0; pass < 2; ++pass) {
            __syncthreads();
            if ((wm >> 1) == pass) {
#pragma unroll
                for (int mi = 0; mi < 4; ++mi) {
                    const int lrow = (wm & 1) * 64 + mi * 16 + lg * 4;
#pragma unroll
                    for (int ni = 0; ni < 4; ++ni) {
                        const int cl = wn * 64 + ni * 16 + lr;
#pragma unroll
                        for (int j = 0; j < 4; ++j) tileF[(lrow + j) * 128 + cl] = acc[mi][ni][j];
                    }
                }
            }
            __syncthreads();
#pragma unroll
            for (int i = tid; i < 128 * 128 / 4; i += 512) {
                int row = i >> 5, c4 = (i & 31) << 2;
                f32x4 vv = *(const f32x4*)&tileF[row * 128 + c4];
                *(f32x4*)&((float*)Cq)[(long)z * cBatch +
                                       (long)(m0 + pass * 128 + row) * ldc + n0 + c4] = vv;
            }
        }
    }
}

// ------------- 2-phase mgemm (128 x NF*32), depth-4 ring — for K8 -------------
template <int NF, int KTOT, bool OUT_BF16, bool HAS_BIAS, bool RSTAT>
__global__ __launch_bounds__(256) void mgemm(
    int gx, int gy,
    const unsigned short* __restrict__ A, long aBatch, long aOff, int lda,
    const unsigned short* __restrict__ B, long bBatch, long bOff, int ldb,
    void* __restrict__ Cq, long cBatch, int ldc,
    const float* __restrict__ bias, float* __restrict__ stats, int statStride) {
    constexpr int AU = 128 * 32;
    constexpr int BU = NF * 32 * 32;
    constexpr int BUFU = AU + BU;
    constexpr int S = KTOT / 32;
    constexpr int LPS = 2 + NF / 2;
    constexpr int COLS = NF * 32;
    __shared__ unsigned short lds[4 * BUFU];

    const int nwg = gridDim.x;
    const int bid = blockIdx.x;
    const int wk = ((bid & 7) * (nwg >> 3)) + (bid >> 3);
    const int bx = wk % gx;
    const int byz = wk / gx;
    const int by = byz % gy;
    const int z = byz / gy;

    const int tid = threadIdx.x;
    const int wave = tid >> 6, lane = tid & 63;
    const int wm = wave >> 1, wn = wave & 1;
    const int lr = lane & 15, lg = lane >> 4;
    const int m0 = by * 128, n0 = bx * COLS;
    const long aB = aOff + (long)z * aBatch;
    const long bB = bOff + (long)z * bBatch;
    const int srow = lane >> 2;
    const int sq   = lane & 3;

    f32x4 acc[4][NF];
#pragma unroll
    for (int i = 0; i < 4; ++i)
#pragma unroll
        for (int j = 0; j < NF; ++j) acc[i][j] = (f32x4){0.f, 0.f, 0.f, 0.f};

    auto stage = [&](int bufu, int kt) {
#pragma unroll
        for (int t = 0; t < 2; ++t) {
            int seg = wave + t * 4;
            int row = seg * 16 + srow;
            int gq = sq ^ ((row >> 1) & 3);
            glds16(A + aB + (long)(m0 + row) * lda + kt + gq * 8, &lds[bufu + seg * 512]);
        }
#pragma unroll
        for (int t = 0; t < NF / 2; ++t) {
            int seg = wave + t * 4;
            int row = seg * 16 + srow;
            int gq = sq ^ ((row >> 1) & 3);
            glds16(B + bB + (long)(n0 + row) * ldb + kt + gq * 8, &lds[bufu + AU + seg * 512]);
        }
    };

    stage(0, 0);
    if (S > 1) stage(BUFU, 32);
    if (S > 2) stage(2 * BUFU, 64);

#pragma unroll
    for (int s = 0; s < S; ++s) {
        const int bufu = (s & 3) * BUFU;
        const unsigned bb = (unsigned)(bufu * 2);
        const int rem = (S - 1 - s) < 2 ? (S - 1 - s) : 2;
        if (rem == 2)      asm volatile("s_waitcnt vmcnt(%0)" ::"i"(2 * LPS) : "memory");
        else if (rem == 1) asm volatile("s_waitcnt vmcnt(%0)" ::"i"(LPS) : "memory");
        else               asm volatile("s_waitcnt vmcnt(0)" ::: "memory");
        asm volatile("s_barrier" ::: "memory");
        i32x4 a4[4], b4[NF];
#pragma unroll
        for (int mi = 0; mi < 4; ++mi) {
            unsigned r = (unsigned)(wm * 64 + mi * 16 + lr);
            unsigned ad = bb + r * 64 + ((unsigned)(lg ^ ((r >> 1) & 3)) * 16);
            asm volatile("ds_read_b128 %0, %1" : "=v"(a4[mi]) : "v"(ad));
        }
#pragma unroll
        for (int ni = 0; ni < NF; ++ni) {
            unsigned r = (unsigned)(wn * NF * 16 + ni * 16 + lr);
            unsigned ad = bb + (unsigned)(AU * 2) + r * 64 + ((unsigned)(lg ^ ((r >> 1) & 3)) * 16);
            asm volatile("ds_read_b128 %0, %1" : "=v"(b4[ni]) : "v"(ad));
        }
        if (s + 3 < S) stage(((s + 3) & 3) * BUFU, (s + 3) * 32);
        asm volatile("s_waitcnt lgkmcnt(0)" ::: "memory");
        __builtin_amdgcn_sched_barrier(0);
        __builtin_amdgcn_s_setprio(1);
#pragma unroll
        for (int ni = 0; ni < NF; ++ni) {
            short8 bh = __builtin_bit_cast(short8, b4[ni]);
#pragma unroll
            for (int mi = 0; mi < 4; ++mi)
                acc[mi][ni] = __builtin_amdgcn_mfma_f32_16x16x32_bf16(
                    __builtin_bit_cast(short8, a4[mi]), bh, acc[mi][ni], 0, 0, 0);
        }
        __builtin_amdgcn_s_setprio(0);
    }

    __syncthreads();
    float* tileF = (float*)lds;      // [128][COLS] f32
#pragma unroll
    for (int mi = 0; mi < 4; ++mi) {
        const int mrow = m0 + wm * 64 + mi * 16 + lg * 4;
        const int lrow = wm * 64 + mi * 16 + lg * 4;
        f32x4 bi = (f32x4){0.f, 0.f, 0.f, 0.f};
        if constexpr (HAS_BIAS) bi = *(const f32x4*)&bias[mrow];
        f32x4 s = (f32x4){0.f, 0.f, 0.f, 0.f}, s2 = s;
#pragma unroll
        for (int ni = 0; ni < NF; ++ni) {
            const int cl = wn * NF * 16 + ni * 16 + lr;
            f32x4 v = acc[mi][ni] + bi;
            if constexpr (RSTAT) { s += v; s2 += v * v; }
#pragma unroll
            for (int j = 0; j < 4; ++j) tileF[(lrow + j) * COLS + cl] = v[j];
        }
        if constexpr (RSTAT) {
#pragma unroll
            for (int m = 1; m < 16; m <<= 1) {
#pragma unroll
                for (int r = 0; r < 4; ++r) {
                    s[r] += __shfl_xor(s[r], m);
                    s2[r] += __shfl_xor(s2[r], m);
                }
            }
            if (lr == 0) {
#pragma unroll
                for (int r = 0; r < 4; ++r) {
                    atomicAdd(&stats[mrow + r], s[r]);
                    atomicAdd(&stats[statStride + mrow + r], s2[r]);
                }
            }
        }
    }
    __syncthreads();
#pragma unroll
    for (int i = tid; i < 128 * COLS / 4; i += 256) {
        int row = i / (COLS / 4), c4 = (i % (COLS / 4)) * 4;
        f32x4 vv = *(const f32x4*)&tileF[row * COLS + c4];
        *(f32x4*)&((float*)Cq)[(long)z * cBatch + (long)(m0 + row) * ldc + n0 + c4] = vv;
    }
}

// raw sums -> per-channel scale/shift
__global__ void finalize_stats(const float* __restrict__ raw, int n, int stride,
                               const float* __restrict__ g, const float* __restrict__ beta,
                               float* __restrict__ osc, float* __restrict__ osh) {
    int ch = blockIdx.x * 256 + threadIdx.x;
    if (ch < n) {
        double mean = (double)raw[ch] / 65536.0;
        double var = (double)raw[stride + ch] / 65536.0 - mean * mean;
        double s = (double)g[ch] / sqrt(var + 1e-5);
        osc[ch] = (float)s;
        osh[ch] = (float)((double)beta[ch] - mean * s);
    }
}

// normalize theta/phi cols (0..255) of YT [65536][384] -> tps rows [th|tl|ph|pl] (512)
__global__ __launch_bounds__(256) void norm_tp(const float* __restrict__ YT,
                                               const float* __restrict__ sc,
                                               const float* __restrict__ sh,
                                               unsigned short* __restrict__ tps) {
    const long total = 64L * 1024 * 64;  // f4 groups (256 cols / 4)
    for (long idx = (long)blockIdx.x * 256 + threadIdx.x; idx < total;
         idx += (long)gridDim.x * 256) {
        long row = idx >> 6;
        int cg = (int)(idx & 63) << 2;
        f32x4 v = *(const f32x4*)&YT[row * 384 + cg];
        f32x4 scv = *(const f32x4*)&sc[cg];
        f32x4 shv = *(const f32x4*)&sh[cg];
        v = v * scv + shv;
        u16x4 h, l;
#pragma unroll
        for (int j = 0; j < 4; ++j) {
            unsigned short hh = f2bf(v[j]);
            h[j] = hh;
            l[j] = f2bf(v[j] - bf2f(hh));
        }
        long rb = row * 512;
        if (cg < 128) {               // theta: th | tl
            *(u16x4*)&tps[rb + cg] = h;
            *(u16x4*)&tps[rb + 128 + cg] = l;
        } else {                      // phi: ph | pl at 256/384
            *(u16x4*)&tps[rb + 128 + cg] = h;
            *(u16x4*)&tps[rb + 256 + cg] = l;
        }
    }
}

// gamma cols (256..383) of YT [65536][384], transpose -> g bf16 [64][128][1024]
__global__ __launch_bounds__(256) void norm_g(const float* __restrict__ YT,
                                              const float* __restrict__ sc,
                                              const float* __restrict__ sh,
                                              unsigned short* __restrict__ g) {
    __shared__ float t[64][68];
    const int b = blockIdx.z, c0 = blockIdx.y * 64, n0 = blockIdx.x * 64;
    const int tid = threadIdx.x;
#pragma unroll
    for (int p = 0; p < 4; ++p) {
        int i = tid + p * 256;
        int n = i >> 4, c4 = (i & 15) << 2;
        f32x4 v = *(const f32x4*)&YT[((long)b * 1024 + n0 + n) * 384 + 256 + c0 + c4];
        f32x4 scv = *(const f32x4*)&sc[256 + c0 + c4];
        f32x4 shv = *(const f32x4*)&sh[256 + c0 + c4];
        v = v * scv + shv;
        *(f32x4*)&t[n][c4] = v;
    }
    __syncthreads();
#pragma unroll
    for (int p = 0; p < 4; ++p) {
        int i = tid + p * 256;
        int c = i >> 4, n4 = (i & 15) << 2;
        u16x4 o;
#pragma unroll
        for (int j = 0; j < 4; ++j) o[j] = f2bf(t[n4 + j][c]);
        *(u16x4*)&g[((long)b * 128 + c0 + c) * 1024 + n0 + n4] = o;
    }
}

// out = x + sc2[oc]*out0 + sh2[oc]; out0 layout == x layout ([64][256][1024])
__global__ __launch_bounds__(256) void final_kernel(const float* __restrict__ x,
                                                    const float* __restrict__ out0,
                                                    const float* __restrict__ sc,
                                                    const float* __restrict__ sh,
                                                    float* __restrict__ out) {
    const long total4 = 64L * 256 * 256;   // f4 groups
    for (long idx = (long)blockIdx.x * 256 + threadIdx.x; idx < total4;
         idx += (long)gridDim.x * 256) {
        long e = idx << 2;
        int oc = (int)((e >> 10) & 255);
        f32x4 xv = *(const f32x4*)&x[e];
        f32x4 ov = *(const f32x4*)&out0[e];
        const float scv = sc[oc], shv = sh[oc];
        f32x4 v;
#pragma unroll
        for (int j = 0; j < 4; ++j) v[j] = xv[j] + ov[j] * scv + shv;
        *(f32x4*)&out[e] = v;
    }
}

extern "C" void kernel_launch(void* const* d_in, const int* in_sizes, int n_in,
                              void* d_out, int out_size, void* d_ws, size_t ws_size,
                              hipStream_t stream) {
    const float* x        = (const float*)d_in[0];
    const float* theta_w  = (const float*)d_in[1];
    const float* theta_b  = (const float*)d_in[2];
    const float* theta_g  = (const float*)d_in[3];
    const float* theta_be = (const float*)d_in[4];
    const float* phi_w    = (const float*)d_in[5];
    const float* phi_b    = (const float*)d_in[6];
    const float* phi_g    = (const float*)d_in[7];
    const float* phi_be   = (const float*)d_in[8];
    const float* gamma_w  = (const float*)d_in[9];
    const float* gamma_b  = (const float*)d_in[10];
    const float* gamma_g  = (const float*)d_in[11];
    const float* gamma_be = (const float*)d_in[12];
    const float* omega_w  = (const float*)d_in[13];
    const float* omega_b  = (const float*)d_in[14];
    const float* omega_g  = (const float*)d_in[15];
    const float* omega_be = (const float*)d_in[16];
    float* out = (float*)d_out;

    const size_t need = (size_t)WS_FLOATS * 4;
    if (ws_size < need) {
        fprintf(stderr, "kernel_launch: ws_size %zu < needed %zu\n", ws_size, need);
        return;
    }
    float* ws = (float*)d_ws;
    unsigned short* Wsp = (unsigned short*)(ws + OFF_WST);
    float* vecs = ws + OFF_VEC;
    float* r1   = ws + OFF_R1;
    float* r2   = ws + OFF_R2;
    float* zs   = ws + OFF_ZS;
    float* sc1  = ws + OFF_SC1;
    float* sh1  = ws + OFF_SH1;
    float* sc2  = ws + OFF_SC2;
    float* sh2  = ws + OFF_SH2;
    float* invz = ws + OFF_INVZ;
    unsigned short* omB = (unsigned short*)(ws + OFF_OM);   // [256][128] bf16
    unsigned short* xs  = (unsigned short*)(ws + OFF_X);    // [65536][512] hi|lo
    unsigned short* tps = (unsigned short*)(ws + OFF_X);    // same region (xs dead)
    float* YT           = ws + OFF_Y;                       // f32 [65536][384]
    unsigned short* P   = (unsigned short*)(ws + OFF_Y);    // bf16 [64][1024][1024] (YT dead)
    float* out0         = ws + OFF_Y;                       // f32 [64][256][1024] (P dead)
    unsigned short* g   = (unsigned short*)(ws + OFF_C);    // [64][128][1024]
    unsigned short* satT= (unsigned short*)(ws + OFF_D);    // [65536][128]

    const int NOMAP = 1 << 30;

    zero_n<<<6, 256, 0, stream>>>(r1, 1344);
    stack_params<<<384, 256, 0, stream>>>(theta_w, theta_b, theta_g, theta_be,
                                          phi_w, phi_b, phi_g, phi_be,
                                          gamma_w, gamma_b, gamma_g, gamma_be,
                                          omega_w, Wsp, vecs, omB);
    transpose_x<<<dim3(16, 4, 64), 256, 0, stream>>>(x, xs);

    // K1 (8-phase): YT[b*1024+n][oc] = xs_trip[n][:] . Wsp[oc][:] + bias[oc]
    mgemm8<12, false, false, true, false, true, false><<<768, 512, 0, stream>>>(
        3, 256,
        xs, 0, 0, 512, 256, 0, -256,
        Wsp, 0, 0, 768, NOMAP, 0, 0,
        YT, 0, 384, vecs, nullptr, r1, 384, nullptr);
    finalize_stats<<<2, 256, 0, stream>>>(r1, 384, 384, vecs + 384, vecs + 768, sc1, sh1);

    norm_tp<<<4096, 256, 0, stream>>>(YT, sc1, sh1, tps);   // overwrites xs
    norm_g<<<dim3(16, 2, 64), 256, 0, stream>>>(YT, sc1, sh1, g);

    // K4 (8-phase): P[n][m] = exp(theta_n.phi_m - 40) bf16 + Z  (K=384 tripled)
    mgemm8<6, true, false, false, false, false, true><<<2048, 512, 0, stream>>>(
        8, 4,
        tps, 524288, 0, 512, 128, 0, -128,
        tps, 524288, 0, 512, 256, 256, 0,
        P, 1048576, 1024, nullptr, nullptr, nullptr, 0, zs);
    invz_kernel<<<1, 64, 0, stream>>>(zs, invz);

    // K7 (8-phase): satT[n][ch] = invz[b] * sum_m P[n][m] g[ch][m]
    mgemm8<16, true, false, false, true, false, false><<<256, 512, 0, stream>>>(
        1, 4,
        P, 1048576, 0, 1024, NOMAP, 0, 0,
        g, 131072, 0, 1024, NOMAP, 0, 0,
        satT, 131072, 128, nullptr, invz, nullptr, 0, nullptr);

    // K8 (2-phase): out0[b][oc][n] = omB[oc][:] . satT[b*1024+n][:] + omega_b[oc]
    // A=omB (M=256, gy=2), B=satT z-batched (gx=8), grid 8*2*64 = 1024; row stats.
    mgemm<4, 128, false, true, true><<<1024, 256, 0, stream>>>(
        8, 2,
        omB, 0, 0, 128,
        satT, 131072, 0, 128,
        out0, 262144, 1024, omega_b, r2, 256);
    finalize_stats<<<1, 256, 0, stream>>>(r2, 256, 256, omega_g, omega_be, sc2, sh2);

    final_kernel<<<2048, 256, 0, stream>>>(x, out0, sc2, sh2, out);
}

// Round 20
// 334.754 us; speedup vs baseline: 1.2556x; 1.2556x over previous
//
#include <hip/hip_runtime.h>
#include <cstdio>

// B=64, CIN=256, CP=128, N=1024. Stacked conv: 384 = theta|phi|gamma.
// r18/r19 lesson: K8 at ~128us under BOTH mgemm8 and 2-phase forms when
// configured A=omB/B=satT -> oc-major out0 in the OFF_Y region; r17's
// A=satT/B=omB -> n-major out0T at OFF_X was provably <68us. r20 restores
// that exact K8 configuration (invz stays fused in K7) + r17 final_kernel
// (LDS transpose). K1/K4/K7 keep the 8-phase mgemm8 (K4 single z=64 launch).
// Precision: K-TRIPLED 3-product via k->slot remaps ([Wh|Wl|Wh]·[xh|xh|xl]).
// Softmax: fixed-offset exp(S-40), Z fused in K4 epilogue, 1/Z in K7 scale.

typedef __attribute__((ext_vector_type(4))) float f32x4;
typedef __attribute__((ext_vector_type(8))) short short8;
typedef __attribute__((ext_vector_type(4))) unsigned short u16x4;
typedef __attribute__((ext_vector_type(8))) unsigned short u16x8;
typedef __attribute__((ext_vector_type(4))) int i32x4;

static constexpr float CEXP = 40.0f;
static constexpr float LOG2E = 1.4426950408889634f;

// ---- workspace layout (floats) ----
static constexpr long OFF_WST  = 0;           // u16[384][768] = 147456 fl
static constexpr long OFF_VEC  = 147456;      // 1152: b|g|beta stacked
static constexpr long OFF_R1   = 148608;      // 768  (zeroed region start)
static constexpr long OFF_R2   = 149376;      // 512
static constexpr long OFF_ZS   = 149888;      // 64   (zeroed: 1344 total)
static constexpr long OFF_SC1  = 149952;      // 384
static constexpr long OFF_SH1  = 150336;      // 384
static constexpr long OFF_SC2  = 150720;      // 256
static constexpr long OFF_SH2  = 150976;      // 256
static constexpr long OFF_INVZ = 151232;      // 64
static constexpr long OFF_OM   = 151296;      // u16[256][128] = 16384 fl
static constexpr long OFF_X    = 262144;                // 16777216 fl: xs/tps u16[65536][512]
                                                        //   -> out0T f32 [65536][256]
static constexpr long OFF_Y    = OFF_X + 16777216;      // 33554432 fl: YT f32 [65536][384]
                                                        //   -> P bf16 [64][1024][1024]
static constexpr long OFF_C    = OFF_Y + 33554432;      // 4194304 fl: g bf16 [64][128][1024]
static constexpr long OFF_D    = OFF_C + 4194304;       // 4194304 fl: satT bf16 [65536][128]
static constexpr long WS_FLOATS = OFF_D + 4194304;      // 58982400 fl = 225 MiB

__device__ __forceinline__ unsigned short f2bf(float f) {
    union { float f; unsigned u; } x; x.f = f;
    unsigned r = x.u + 0x7FFF + ((x.u >> 16) & 1);
    return (unsigned short)(r >> 16);
}
__device__ __forceinline__ float bf2f(unsigned short h) {
    union { unsigned u; float f; } x; x.u = ((unsigned)h) << 16; return x.f;
}
__device__ __forceinline__ void glds16(const void* g, void* l) {
    __builtin_amdgcn_global_load_lds(
        (const __attribute__((address_space(1))) unsigned int*)g,
        (__attribute__((address_space(3))) unsigned int*)l, 16, 0, 0);
}

// ---------------- utility kernels ----------------
__global__ void zero_n(float* p, int n) {
    int i = blockIdx.x * 256 + threadIdx.x;
    if (i < n) p[i] = 0.f;
}

__global__ void invz_kernel(const float* zs, float* invz) {
    int i = threadIdx.x;
    if (i < 64) invz[i] = 1.0f / zs[i];
}

// stack theta|phi|gamma weights K-tripled [384][768]; omega -> bf16 [256][128]
__global__ void stack_params(const float* tw, const float* tb, const float* tg, const float* tbe,
                             const float* pw, const float* pb, const float* pg, const float* pbe,
                             const float* gw, const float* gb, const float* gg, const float* gbe,
                             const float* ow,
                             unsigned short* Wsp, float* vecs, unsigned short* omB) {
    int i = blockIdx.x * 256 + threadIdx.x;
    if (i < 98304) {
        int o = i >> 8, c = i & 255;
        float v = (o < 128) ? tw[o * 256 + c] : (o < 256) ? pw[(o - 128) * 256 + c]
                                                          : gw[(o - 256) * 256 + c];
        unsigned short hi = f2bf(v);
        unsigned short lo = f2bf(v - bf2f(hi));
        Wsp[(long)o * 768 + c] = hi;
        Wsp[(long)o * 768 + 256 + c] = lo;
        Wsp[(long)o * 768 + 512 + c] = hi;
    }
    if (i < 32768) omB[i] = f2bf(ow[i]);
    if (i < 384) {
        float b  = (i < 128) ? tb[i]  : (i < 256) ? pb[i - 128]  : gb[i - 256];
        float g  = (i < 128) ? tg[i]  : (i < 256) ? pg[i - 128]  : gg[i - 256];
        float be = (i < 128) ? tbe[i] : (i < 256) ? pbe[i - 128] : gbe[i - 256];
        vecs[i] = b; vecs[384 + i] = g; vecs[768 + i] = be;
    }
}

// x [64][256][1024] f32 -> xs [64][1024][512] bf16 rows [xh | xl]
__global__ __launch_bounds__(256) void transpose_x(const float* __restrict__ x,
                                                   unsigned short* __restrict__ xs) {
    __shared__ float t[64][68];
    const int b = blockIdx.z, c0 = blockIdx.y * 64, n0 = blockIdx.x * 64;
    const int tid = threadIdx.x;
#pragma unroll
    for (int p = 0; p < 4; ++p) {
        int i = tid + p * 256;
        int c = i >> 4, n4 = (i & 15) << 2;
        f32x4 v = *(const f32x4*)&x[((long)b * 256 + c0 + c) * 1024 + n0 + n4];
        *(f32x4*)&t[c][n4] = v;
    }
    __syncthreads();
#pragma unroll
    for (int p = 0; p < 4; ++p) {
        int i = tid + p * 256;
        int n = i >> 4, c4 = (i & 15) << 2;
        u16x4 h, l;
#pragma unroll
        for (int j = 0; j < 4; ++j) {
            float v = t[c4 + j][n];
            unsigned short hh = f2bf(v);
            h[j] = hh;
            l[j] = f2bf(v - bf2f(hh));
        }
        long o = ((long)b * 1024 + n0 + n) * 512 + c0 + c4;
        *(u16x4*)&xs[o] = h;
        *(u16x4*)&xs[o + 256] = l;
    }
}

// ================= 8-phase GEMM: BM=256, BN=128, BK=64, 8 waves =================
template <int NT, bool OUT_BF16, bool HAS_RBIAS, bool HAS_CBIAS, bool HAS_SCALE,
          bool CSTAT, bool EXPZ>
__global__ __launch_bounds__(512) void mgemm8(
    int gx, int gy,
    const unsigned short* __restrict__ A, long aBatch, long aOff, int lda,
    int athr, int adlo, int adhi,
    const unsigned short* __restrict__ B, long bBatch, long bOff, int ldb,
    int bthr, int bdlo, int bdhi,
    void* __restrict__ Cq, long cBatch, int ldc,
    const float* __restrict__ bias, const float* __restrict__ bscale,
    float* __restrict__ stats, int statStride, float* __restrict__ zsum) {
    constexpr int AU = 256 * 64;   // u16 (32 KB)
    constexpr int BU = 128 * 64;   // u16 (16 KB)
    constexpr int BUFU = AU + BU;  // 48 KB
    __shared__ unsigned short lds[3 * BUFU];   // 144 KB ring; reused by epilogue

    const int nwg = gridDim.x, bid = blockIdx.x;
    const int wk = ((bid & 7) * (nwg >> 3)) + (bid >> 3);   // nwg % 8 == 0
    const int bx = wk % gx;
    const int byz = wk / gx;
    const int by = byz % gy;
    const int z = byz / gy;

    const int tid = threadIdx.x;
    const int wave = tid >> 6, lane = tid & 63;
    const int wm = wave >> 1, wn = wave & 1;            // 4 x 2 wave grid
    const int lr = lane & 15, lg = lane >> 4;
    const int m0 = by * 256, n0 = bx * 128;
    const long aB = aOff + (long)z * aBatch;
    const long bB = bOff + (long)z * bBatch;
    const int grow = lane >> 3, gq = lane & 7;          // staging lane split

    f32x4 acc[4][4];
#pragma unroll
    for (int i = 0; i < 4; ++i)
#pragma unroll
        for (int j = 0; j < 4; ++j) acc[i][j] = (f32x4){0.f, 0.f, 0.f, 0.f};

    auto stageA = [&](int buf, int kt, int t) {
        const int ka = (kt < athr ? kt + adlo : kt + adhi);
        int seg = wave + t * 8;                 // 32 segs of 8 rows (1 KB each)
        int row = seg * 8 + grow;
        glds16(A + aB + (long)(m0 + row) * lda + ka + ((gq ^ (row & 7)) << 3),
               &lds[buf + seg * 512]);
    };
    auto stageB = [&](int buf, int kt, int t) {
        const int kb = (kt < bthr ? kt + bdlo : kt + bdhi);
        int seg = wave + t * 8;                 // 16 segs
        int row = seg * 8 + grow;
        glds16(B + bB + (long)(n0 + row) * ldb + kb + ((gq ^ (row & 7)) << 3),
               &lds[buf + AU + seg * 512]);
    };
    auto stage_all = [&](int buf, int kt) {
#pragma unroll
        for (int t = 0; t < 4; ++t) stageA(buf, kt, t);
#pragma unroll
        for (int t = 0; t < 2; ++t) stageB(buf, kt, t);
    };

    stage_all(0, 0);
    if (NT > 1) stage_all(BUFU, 64);

#pragma unroll
    for (int t = 0; t < NT; ++t) {
        const unsigned bb = (unsigned)(((t % 3) * BUFU) * 2);   // byte base
        if (t + 1 < NT) asm volatile("s_waitcnt vmcnt(6)" ::: "memory");
        else            asm volatile("s_waitcnt vmcnt(0)" ::: "memory");
        asm volatile("s_barrier" ::: "memory");   // tile t resident for all waves
        const int sbuf = ((t + 2) % 3) * BUFU;
        const int skt = (t + 2) * 64;
#pragma unroll
        for (int p = 0; p < 2; ++p) {
            i32x4 a4[4], b4[4];
#pragma unroll
            for (int mi = 0; mi < 4; ++mi) {
                unsigned r = (unsigned)(wm * 64 + mi * 16 + lr);
                unsigned ad = bb + r * 128 + ((unsigned)(((p << 2) | lg) ^ (r & 7)) << 4);
                asm volatile("ds_read_b128 %0, %1" : "=v"(a4[mi]) : "v"(ad));
            }
#pragma unroll
            for (int ni = 0; ni < 4; ++ni) {
                unsigned r = (unsigned)(wn * 64 + ni * 16 + lr);
                unsigned ad = bb + (unsigned)(AU * 2) + r * 128 +
                              ((unsigned)(((p << 2) | lg) ^ (r & 7)) << 4);
                asm volatile("ds_read_b128 %0, %1" : "=v"(b4[ni]) : "v"(ad));
            }
            if (t + 2 < NT) {           // half of tile t+2's staging per phase
                if (p == 0) { stageA(sbuf, skt, 0); stageA(sbuf, skt, 1); stageA(sbuf, skt, 2); }
                else        { stageA(sbuf, skt, 3); stageB(sbuf, skt, 0); stageB(sbuf, skt, 1); }
            }
            asm volatile("s_waitcnt lgkmcnt(0)" ::: "memory");
            __builtin_amdgcn_sched_barrier(0);
            __builtin_amdgcn_s_setprio(1);
#pragma unroll
            for (int ni = 0; ni < 4; ++ni) {
                short8 bh = __builtin_bit_cast(short8, b4[ni]);
#pragma unroll
                for (int mi = 0; mi < 4; ++mi)
                    acc[mi][ni] = __builtin_amdgcn_mfma_f32_16x16x32_bf16(
                        __builtin_bit_cast(short8, a4[mi]), bh, acc[mi][ni], 0, 0, 0);
            }
            __builtin_amdgcn_s_setprio(0);
            if (p == 0) asm volatile("s_barrier" ::: "memory");
        }
    }

    // ---- transform: acc = acc*scale + row_bias + col_bias ----
    const float sc = HAS_SCALE ? bscale[z] : 1.0f;
#pragma unroll
    for (int mi = 0; mi < 4; ++mi) {
        const int mrow = m0 + wm * 64 + mi * 16 + lg * 4;
        f32x4 rb = (f32x4){0.f, 0.f, 0.f, 0.f};
        if constexpr (HAS_RBIAS) rb = *(const f32x4*)&bias[mrow];
#pragma unroll
        for (int ni = 0; ni < 4; ++ni) {
            float cbv = HAS_CBIAS ? bias[n0 + wn * 64 + ni * 16 + lr] : 0.0f;
            acc[mi][ni] = acc[mi][ni] * sc + rb + (f32x4){cbv, cbv, cbv, cbv};
        }
    }
    if constexpr (CSTAT) {
#pragma unroll
        for (int ni = 0; ni < 4; ++ni) {
            float a = 0.f, b2 = 0.f;
#pragma unroll
            for (int mi = 0; mi < 4; ++mi) {
                f32x4 v = acc[mi][ni];
                a += v[0] + v[1] + v[2] + v[3];
                b2 += v[0] * v[0] + v[1] * v[1] + v[2] * v[2] + v[3] * v[3];
            }
            a += __shfl_xor(a, 16); a += __shfl_xor(a, 32);
            b2 += __shfl_xor(b2, 16); b2 += __shfl_xor(b2, 32);
            if (lg == 0) {
                const int col = n0 + wn * 64 + ni * 16 + lr;
                atomicAdd(&stats[col], a);
                atomicAdd(&stats[statStride + col], b2);
            }
        }
    }

    if constexpr (OUT_BF16) {
        __syncthreads();
        unsigned short* tileH = lds;          // [256][128] bf16 = 64 KB
        float zacc = 0.f;
#pragma unroll
        for (int mi = 0; mi < 4; ++mi) {
            const int lrow = wm * 64 + mi * 16 + lg * 4;
#pragma unroll
            for (int ni = 0; ni < 4; ++ni) {
                const int cl = wn * 64 + ni * 16 + lr;
                f32x4 v = acc[mi][ni];
#pragma unroll
                for (int j = 0; j < 4; ++j) {
                    unsigned short o;
                    if constexpr (EXPZ) {
                        float e = exp2f((v[j] - CEXP) * LOG2E);
                        o = f2bf(e);
                        zacc += bf2f(o);
                    } else {
                        o = f2bf(v[j]);
                    }
                    tileH[(lrow + j) * 128 + cl] = o;
                }
            }
        }
        __syncthreads();
#pragma unroll
        for (int i = tid; i < 256 * 128 / 8; i += 512) {
            int row = i >> 4, c8 = (i & 15) << 3;
            u16x8 vv = *(const u16x8*)&tileH[row * 128 + c8];
            *(u16x8*)&((unsigned short*)Cq)[(long)z * cBatch + (long)(m0 + row) * ldc + n0 + c8] = vv;
        }
        if constexpr (EXPZ) {
            __syncthreads();
            float* red = (float*)lds;
            red[tid] = zacc;
            __syncthreads();
            for (int o = 256; o > 0; o >>= 1) {
                if (tid < o) red[tid] += red[tid + o];
                __syncthreads();
            }
            if (tid == 0) atomicAdd(&zsum[z], red[0]);
        }
    } else {
        // f32 output in two 128-row passes (64 KB tile each)
        float* tileF = (float*)lds;
#pragma unroll
        for (int pass = 0; pass < 2; ++pass) {
            __syncthreads();
            if ((wm >> 1) == pass) {
#pragma unroll
                for (int mi = 0; mi < 4; ++mi) {
                    const int lrow = (wm & 1) * 64 + mi * 16 + lg * 4;
#pragma unroll
                    for (int ni = 0; ni < 4; ++ni) {
                        const int cl = wn * 64 + ni * 16 + lr;
#pragma unroll
                        for (int j = 0; j < 4; ++j) tileF[(lrow + j) * 128 + cl] = acc[mi][ni][j];
                    }
                }
            }
            __syncthreads();
#pragma unroll
            for (int i = tid; i < 128 * 128 / 4; i += 512) {
                int row = i >> 5, c4 = (i & 31) << 2;
                f32x4 vv = *(const f32x4*)&tileF[row * 128 + c4];
                *(f32x4*)&((float*)Cq)[(long)z * cBatch +
                                       (long)(m0 + pass * 128 + row) * ldc + n0 + c4] = vv;
            }
        }
    }
}

// ------------- 2-phase mgemm (128 x NF*32), depth-4 ring — K8 (f32 out) -------------
template <int NF, int KTOT, bool HAS_RBIAS, bool HAS_CBIAS, bool RSTAT, bool CSTAT>
__global__ __launch_bounds__(256) void mgemm(
    int gx, int gy,
    const unsigned short* __restrict__ A, long aBatch, long aOff, int lda,
    const unsigned short* __restrict__ B, long bBatch, long bOff, int ldb,
    void* __restrict__ Cq, long cBatch, int ldc,
    const float* __restrict__ bias, float* __restrict__ stats, int statStride) {
    constexpr int AU = 128 * 32;
    constexpr int BU = NF * 32 * 32;
    constexpr int BUFU = AU + BU;
    constexpr int S = KTOT / 32;
    constexpr int LPS = 2 + NF / 2;
    constexpr int COLS = NF * 32;
    __shared__ unsigned short lds[4 * BUFU];

    const int nwg = gridDim.x;
    const int bid = blockIdx.x;
    const int wk = ((bid & 7) * (nwg >> 3)) + (bid >> 3);
    const int bx = wk % gx;
    const int byz = wk / gx;
    const int by = byz % gy;
    const int z = byz / gy;

    const int tid = threadIdx.x;
    const int wave = tid >> 6, lane = tid & 63;
    const int wm = wave >> 1, wn = wave & 1;
    const int lr = lane & 15, lg = lane >> 4;
    const int m0 = by * 128, n0 = bx * COLS;
    const long aB = aOff + (long)z * aBatch;
    const long bB = bOff + (long)z * bBatch;
    const int srow = lane >> 2;
    const int sq   = lane & 3;

    f32x4 acc[4][NF];
#pragma unroll
    for (int i = 0; i < 4; ++i)
#pragma unroll
        for (int j = 0; j < NF; ++j) acc[i][j] = (f32x4){0.f, 0.f, 0.f, 0.f};

    auto stage = [&](int bufu, int kt) {
#pragma unroll
        for (int t = 0; t < 2; ++t) {
            int seg = wave + t * 4;
            int row = seg * 16 + srow;
            int gq = sq ^ ((row >> 1) & 3);
            glds16(A + aB + (long)(m0 + row) * lda + kt + gq * 8, &lds[bufu + seg * 512]);
        }
#pragma unroll
        for (int t = 0; t < NF / 2; ++t) {
            int seg = wave + t * 4;
            int row = seg * 16 + srow;
            int gq = sq ^ ((row >> 1) & 3);
            glds16(B + bB + (long)(n0 + row) * ldb + kt + gq * 8, &lds[bufu + AU + seg * 512]);
        }
    };

    stage(0, 0);
    if (S > 1) stage(BUFU, 32);
    if (S > 2) stage(2 * BUFU, 64);

#pragma unroll
    for (int s = 0; s < S; ++s) {
        const int bufu = (s & 3) * BUFU;
        const unsigned bb = (unsigned)(bufu * 2);
        const int rem = (S - 1 - s) < 2 ? (S - 1 - s) : 2;
        if (rem == 2)      asm volatile("s_waitcnt vmcnt(%0)" ::"i"(2 * LPS) : "memory");
        else if (rem == 1) asm volatile("s_waitcnt vmcnt(%0)" ::"i"(LPS) : "memory");
        else               asm volatile("s_waitcnt vmcnt(0)" ::: "memory");
        asm volatile("s_barrier" ::: "memory");
        i32x4 a4[4], b4[NF];
#pragma unroll
        for (int mi = 0; mi < 4; ++mi) {
            unsigned r = (unsigned)(wm * 64 + mi * 16 + lr);
            unsigned ad = bb + r * 64 + ((unsigned)(lg ^ ((r >> 1) & 3)) * 16);
            asm volatile("ds_read_b128 %0, %1" : "=v"(a4[mi]) : "v"(ad));
        }
#pragma unroll
        for (int ni = 0; ni < NF; ++ni) {
            unsigned r = (unsigned)(wn * NF * 16 + ni * 16 + lr);
            unsigned ad = bb + (unsigned)(AU * 2) + r * 64 + ((unsigned)(lg ^ ((r >> 1) & 3)) * 16);
            asm volatile("ds_read_b128 %0, %1" : "=v"(b4[ni]) : "v"(ad));
        }
        if (s + 3 < S) stage(((s + 3) & 3) * BUFU, (s + 3) * 32);
        asm volatile("s_waitcnt lgkmcnt(0)" ::: "memory");
        __builtin_amdgcn_sched_barrier(0);
        __builtin_amdgcn_s_setprio(1);
#pragma unroll
        for (int ni = 0; ni < NF; ++ni) {
            short8 bh = __builtin_bit_cast(short8, b4[ni]);
#pragma unroll
            for (int mi = 0; mi < 4; ++mi)
                acc[mi][ni] = __builtin_amdgcn_mfma_f32_16x16x32_bf16(
                    __builtin_bit_cast(short8, a4[mi]), bh, acc[mi][ni], 0, 0, 0);
        }
        __builtin_amdgcn_s_setprio(0);
    }

    __syncthreads();
    float* tileF = (float*)lds;      // [128][COLS] f32
    float scol[NF], s2col[NF];
    if constexpr (CSTAT) {
#pragma unroll
        for (int ni = 0; ni < NF; ++ni) { scol[ni] = 0.f; s2col[ni] = 0.f; }
    }
#pragma unroll
    for (int mi = 0; mi < 4; ++mi) {
        const int mrow = m0 + wm * 64 + mi * 16 + lg * 4;
        const int lrow = wm * 64 + mi * 16 + lg * 4;
        f32x4 bi = (f32x4){0.f, 0.f, 0.f, 0.f};
        if constexpr (HAS_RBIAS) bi = *(const f32x4*)&bias[mrow];
        f32x4 s = (f32x4){0.f, 0.f, 0.f, 0.f}, s2 = s;
#pragma unroll
        for (int ni = 0; ni < NF; ++ni) {
            const int cl = wn * NF * 16 + ni * 16 + lr;
            f32x4 v = acc[mi][ni] + bi;
            if constexpr (HAS_CBIAS) {
                float bc = bias[n0 + cl];
                v += (f32x4){bc, bc, bc, bc};
            }
            if constexpr (RSTAT) { s += v; s2 += v * v; }
            if constexpr (CSTAT) {
                scol[ni] += v[0] + v[1] + v[2] + v[3];
                s2col[ni] += v[0] * v[0] + v[1] * v[1] + v[2] * v[2] + v[3] * v[3];
            }
#pragma unroll
            for (int j = 0; j < 4; ++j) tileF[(lrow + j) * COLS + cl] = v[j];
        }
        if constexpr (RSTAT) {
#pragma unroll
            for (int m = 1; m < 16; m <<= 1) {
#pragma unroll
                for (int r = 0; r < 4; ++r) {
                    s[r] += __shfl_xor(s[r], m);
                    s2[r] += __shfl_xor(s2[r], m);
                }
            }
            if (lr == 0) {
#pragma unroll
                for (int r = 0; r < 4; ++r) {
                    atomicAdd(&stats[mrow + r], s[r]);
                    atomicAdd(&stats[statStride + mrow + r], s2[r]);
                }
            }
        }
    }
    if constexpr (CSTAT) {
#pragma unroll
        for (int ni = 0; ni < NF; ++ni) {
            float a = scol[ni], b2 = s2col[ni];
            a += __shfl_xor(a, 16); a += __shfl_xor(a, 32);
            b2 += __shfl_xor(b2, 16); b2 += __shfl_xor(b2, 32);
            if (lg == 0) {
                const int col = n0 + wn * NF * 16 + ni * 16 + lr;
                atomicAdd(&stats[col], a);
                atomicAdd(&stats[statStride + col], b2);
            }
        }
    }
    __syncthreads();
#pragma unroll
    for (int i = tid; i < 128 * COLS / 4; i += 256) {
        int row = i / (COLS / 4), c4 = (i % (COLS / 4)) * 4;
        f32x4 vv = *(const f32x4*)&tileF[row * COLS + c4];
        *(f32x4*)&((float*)Cq)[(long)z * cBatch + (long)(m0 + row) * ldc + n0 + c4] = vv;
    }
}

// raw sums -> per-channel scale/shift
__global__ void finalize_stats(const float* __restrict__ raw, int n, int stride,
                               const float* __restrict__ g, const float* __restrict__ beta,
                               float* __restrict__ osc, float* __restrict__ osh) {
    int ch = blockIdx.x * 256 + threadIdx.x;
    if (ch < n) {
        double mean = (double)raw[ch] / 65536.0;
        double var = (double)raw[stride + ch] / 65536.0 - mean * mean;
        double s = (double)g[ch] / sqrt(var + 1e-5);
        osc[ch] = (float)s;
        osh[ch] = (float)((double)beta[ch] - mean * s);
    }
}

// normalize theta/phi cols (0..255) of YT [65536][384] -> tps rows [th|tl|ph|pl] (512)
__global__ __launch_bounds__(256) void norm_tp(const float* __restrict__ YT,
                                               const float* __restrict__ sc,
                                               const float* __restrict__ sh,
                                               unsigned short* __restrict__ tps) {
    const long total = 64L * 1024 * 64;  // f4 groups (256 cols / 4)
    for (long idx = (long)blockIdx.x * 256 + threadIdx.x; idx < total;
         idx += (long)gridDim.x * 256) {
        long row = idx >> 6;
        int cg = (int)(idx & 63) << 2;
        f32x4 v = *(const f32x4*)&YT[row * 384 + cg];
        f32x4 scv = *(const f32x4*)&sc[cg];
        f32x4 shv = *(const f32x4*)&sh[cg];
        v = v * scv + shv;
        u16x4 h, l;
#pragma unroll
        for (int j = 0; j < 4; ++j) {
            unsigned short hh = f2bf(v[j]);
            h[j] = hh;
            l[j] = f2bf(v[j] - bf2f(hh));
        }
        long rb = row * 512;
        if (cg < 128) {               // theta: th | tl
            *(u16x4*)&tps[rb + cg] = h;
            *(u16x4*)&tps[rb + 128 + cg] = l;
        } else {                      // phi: ph | pl at 256/384
            *(u16x4*)&tps[rb + 128 + cg] = h;
            *(u16x4*)&tps[rb + 256 + cg] = l;
        }
    }
}

// gamma cols (256..383) of YT [65536][384], transpose -> g bf16 [64][128][1024]
__global__ __launch_bounds__(256) void norm_g(const float* __restrict__ YT,
                                              const float* __restrict__ sc,
                                              const float* __restrict__ sh,
                                              unsigned short* __restrict__ g) {
    __shared__ float t[64][68];
    const int b = blockIdx.z, c0 = blockIdx.y * 64, n0 = blockIdx.x * 64;
    const int tid = threadIdx.x;
#pragma unroll
    for (int p = 0; p < 4; ++p) {
        int i = tid + p * 256;
        int n = i >> 4, c4 = (i & 15) << 2;
        f32x4 v = *(const f32x4*)&YT[((long)b * 1024 + n0 + n) * 384 + 256 + c0 + c4];
        f32x4 scv = *(const f32x4*)&sc[256 + c0 + c4];
        f32x4 shv = *(const f32x4*)&sh[256 + c0 + c4];
        v = v * scv + shv;
        *(f32x4*)&t[n][c4] = v;
    }
    __syncthreads();
#pragma unroll
    for (int p = 0; p < 4; ++p) {
        int i = tid + p * 256;
        int c = i >> 4, n4 = (i & 15) << 2;
        u16x4 o;
#pragma unroll
        for (int j = 0; j < 4; ++j) o[j] = f2bf(t[n4 + j][c]);
        *(u16x4*)&g[((long)b * 128 + c0 + c) * 1024 + n0 + n4] = o;
    }
}

// out[b][oc][n] = x + sc2[oc]*out0T[b][n][oc] + sh2[oc]  (LDS tile transpose)
__global__ __launch_bounds__(256) void final_kernel(const float* __restrict__ x,
                                                    const float* __restrict__ out0T,
                                                    const float* __restrict__ sc,
                                                    const float* __restrict__ sh,
                                                    float* __restrict__ out) {
    __shared__ float t[64][68];
    const int b = blockIdx.z, oc0 = blockIdx.y * 64, n0 = blockIdx.x * 64;
    const int tid = threadIdx.x;
#pragma unroll
    for (int p = 0; p < 4; ++p) {
        int i = tid + p * 256;
        int n = i >> 4, c4 = (i & 15) << 2;
        f32x4 v = *(const f32x4*)&out0T[((long)b * 1024 + n0 + n) * 256 + oc0 + c4];
        *(f32x4*)&t[n][c4] = v;
    }
    __syncthreads();
#pragma unroll
    for (int p = 0; p < 4; ++p) {
        int i = tid + p * 256;
        int oc = i >> 4, n4 = (i & 15) << 2;
        const float scv = sc[oc0 + oc], shv = sh[oc0 + oc];
        long o = ((long)b * 256 + oc0 + oc) * 1024 + n0 + n4;
        f32x4 xv = *(const f32x4*)&x[o];
        f32x4 v;
#pragma unroll
        for (int j = 0; j < 4; ++j) v[j] = xv[j] + t[n4 + j][oc] * scv + shv;
        *(f32x4*)&out[o] = v;
    }
}

extern "C" void kernel_launch(void* const* d_in, const int* in_sizes, int n_in,
                              void* d_out, int out_size, void* d_ws, size_t ws_size,
                              hipStream_t stream) {
    const float* x        = (const float*)d_in[0];
    const float* theta_w  = (const float*)d_in[1];
    const float* theta_b  = (const float*)d_in[2];
    const float* theta_g  = (const float*)d_in[3];
    const float* theta_be = (const float*)d_in[4];
    const float* phi_w    = (const float*)d_in[5];
    const float* phi_b    = (const float*)d_in[6];
    const float* phi_g    = (const float*)d_in[7];
    const float* phi_be   = (const float*)d_in[8];
    const float* gamma_w  = (const float*)d_in[9];
    const float* gamma_b  = (const float*)d_in[10];
    const float* gamma_g  = (const float*)d_in[11];
    const float* gamma_be = (const float*)d_in[12];
    const float* omega_w  = (const float*)d_in[13];
    const float* omega_b  = (const float*)d_in[14];
    const float* omega_g  = (const float*)d_in[15];
    const float* omega_be = (const float*)d_in[16];
    float* out = (float*)d_out;

    const size_t need = (size_t)WS_FLOATS * 4;
    if (ws_size < need) {
        fprintf(stderr, "kernel_launch: ws_size %zu < needed %zu\n", ws_size, need);
        return;
    }
    float* ws = (float*)d_ws;
    unsigned short* Wsp = (unsigned short*)(ws + OFF_WST);
    float* vecs = ws + OFF_VEC;
    float* r1   = ws + OFF_R1;
    float* r2   = ws + OFF_R2;
    float* zs   = ws + OFF_ZS;
    float* sc1  = ws + OFF_SC1;
    float* sh1  = ws + OFF_SH1;
    float* sc2  = ws + OFF_SC2;
    float* sh2  = ws + OFF_SH2;
    float* invz = ws + OFF_INVZ;
    unsigned short* omB = (unsigned short*)(ws + OFF_OM);   // [256][128] bf16
    unsigned short* xs  = (unsigned short*)(ws + OFF_X);    // [65536][512] hi|lo
    unsigned short* tps = (unsigned short*)(ws + OFF_X);    // same region (xs dead)
    float* out0T        = ws + OFF_X;                       // f32 [65536][256] (tps dead)
    float* YT           = ws + OFF_Y;                       // f32 [65536][384]
    unsigned short* P   = (unsigned short*)(ws + OFF_Y);    // bf16 [64][1024][1024] (YT dead)
    unsigned short* g   = (unsigned short*)(ws + OFF_C);    // [64][128][1024]
    unsigned short* satT= (unsigned short*)(ws + OFF_D);    // [65536][128]

    const int NOMAP = 1 << 30;

    zero_n<<<6, 256, 0, stream>>>(r1, 1344);
    stack_params<<<384, 256, 0, stream>>>(theta_w, theta_b, theta_g, theta_be,
                                          phi_w, phi_b, phi_g, phi_be,
                                          gamma_w, gamma_b, gamma_g, gamma_be,
                                          omega_w, Wsp, vecs, omB);
    transpose_x<<<dim3(16, 4, 64), 256, 0, stream>>>(x, xs);

    // K1 (8-phase): YT[b*1024+n][oc] = xs_trip[n][:] . Wsp[oc][:] + bias[oc]
    mgemm8<12, false, false, true, false, true, false><<<768, 512, 0, stream>>>(
        3, 256,
        xs, 0, 0, 512, 256, 0, -256,
        Wsp, 0, 0, 768, NOMAP, 0, 0,
        YT, 0, 384, vecs, nullptr, r1, 384, nullptr);
    finalize_stats<<<2, 256, 0, stream>>>(r1, 384, 384, vecs + 384, vecs + 768, sc1, sh1);

    norm_tp<<<4096, 256, 0, stream>>>(YT, sc1, sh1, tps);   // overwrites xs
    norm_g<<<dim3(16, 2, 64), 256, 0, stream>>>(YT, sc1, sh1, g);

    // K4 (8-phase): P[n][m] = exp(theta_n.phi_m - 40) bf16 + Z  (K=384 tripled)
    mgemm8<6, true, false, false, false, false, true><<<2048, 512, 0, stream>>>(
        8, 4,
        tps, 524288, 0, 512, 128, 0, -128,
        tps, 524288, 0, 512, 256, 256, 0,
        P, 1048576, 1024, nullptr, nullptr, nullptr, 0, zs);
    invz_kernel<<<1, 64, 0, stream>>>(zs, invz);

    // K7 (8-phase): satT[n][ch] = invz[b] * sum_m P[n][m] g[ch][m]
    mgemm8<16, true, false, false, true, false, false><<<256, 512, 0, stream>>>(
        1, 4,
        P, 1048576, 0, 1024, NOMAP, 0, 0,
        g, 131072, 0, 1024, NOMAP, 0, 0,
        satT, 131072, 128, nullptr, invz, nullptr, 0, nullptr);

    // K8 (2-phase, r17-proven config): out0T[b*1024+n][oc] = satT[n][:].omB[oc][:]
    //   + omega_b[oc]; A=satT, B=omB, out n-major at OFF_X; col bias + col stats.
    mgemm<4, 128, false, true, false, true><<<1024, 256, 0, stream>>>(
        2, 8,
        satT, 131072, 0, 128,
        omB, 0, 0, 128,
        out0T, 262144, 256, omega_b, r2, 256);
    finalize_stats<<<1, 256, 0, stream>>>(r2, 256, 256, omega_g, omega_be, sc2, sh2);

    final_kernel<<<dim3(16, 4, 64), 256, 0, stream>>>(x, out0T, sc2, sh2, out);
}

// Round 21
// 328.139 us; speedup vs baseline: 1.2809x; 1.0202x over previous
//
#include <hip/hip_runtime.h>
#include <cstdio>

// B=64, CIN=256, CP=128, N=1024. Stacked conv: 384 = theta|phi|gamma.
// r20 best 334.8us. Top dispatch now K7 (mgemm8 NT=16, 1 block/CU, 172 TF —
// L3-latency-bound, no co-resident block to overlap). r21: K7 -> 2-phase
// mgemm (64KB LDS -> 2 blocks/CU, historically ~276 TF on L3-stream shapes),
// extended with bf16-out + per-z scale (invz). K1/K4 keep mgemm8; K8 keeps
// the r20-proven 2-phase f32 config (A=satT,B=omB, n-major out0T at OFF_X).
// Precision: K-TRIPLED 3-product via k->slot remaps ([Wh|Wl|Wh]·[xh|xh|xl]).
// Softmax: fixed-offset exp(S-40), Z fused in K4 epilogue, 1/Z in K7 scale.

typedef __attribute__((ext_vector_type(4))) float f32x4;
typedef __attribute__((ext_vector_type(8))) short short8;
typedef __attribute__((ext_vector_type(4))) unsigned short u16x4;
typedef __attribute__((ext_vector_type(8))) unsigned short u16x8;
typedef __attribute__((ext_vector_type(4))) int i32x4;

static constexpr float CEXP = 40.0f;
static constexpr float LOG2E = 1.4426950408889634f;

// ---- workspace layout (floats) ----
static constexpr long OFF_WST  = 0;           // u16[384][768] = 147456 fl
static constexpr long OFF_VEC  = 147456;      // 1152: b|g|beta stacked
static constexpr long OFF_R1   = 148608;      // 768  (zeroed region start)
static constexpr long OFF_R2   = 149376;      // 512
static constexpr long OFF_ZS   = 149888;      // 64   (zeroed: 1344 total)
static constexpr long OFF_SC1  = 149952;      // 384
static constexpr long OFF_SH1  = 150336;      // 384
static constexpr long OFF_SC2  = 150720;      // 256
static constexpr long OFF_SH2  = 150976;      // 256
static constexpr long OFF_INVZ = 151232;      // 64
static constexpr long OFF_OM   = 151296;      // u16[256][128] = 16384 fl
static constexpr long OFF_X    = 262144;                // 16777216 fl: xs/tps u16[65536][512]
                                                        //   -> out0T f32 [65536][256]
static constexpr long OFF_Y    = OFF_X + 16777216;      // 33554432 fl: YT f32 [65536][384]
                                                        //   -> P bf16 [64][1024][1024]
static constexpr long OFF_C    = OFF_Y + 33554432;      // 4194304 fl: g bf16 [64][128][1024]
static constexpr long OFF_D    = OFF_C + 4194304;       // 4194304 fl: satT bf16 [65536][128]
static constexpr long WS_FLOATS = OFF_D + 4194304;      // 58982400 fl = 225 MiB

__device__ __forceinline__ unsigned short f2bf(float f) {
    union { float f; unsigned u; } x; x.f = f;
    unsigned r = x.u + 0x7FFF + ((x.u >> 16) & 1);
    return (unsigned short)(r >> 16);
}
__device__ __forceinline__ float bf2f(unsigned short h) {
    union { unsigned u; float f; } x; x.u = ((unsigned)h) << 16; return x.f;
}
__device__ __forceinline__ void glds16(const void* g, void* l) {
    __builtin_amdgcn_global_load_lds(
        (const __attribute__((address_space(1))) unsigned int*)g,
        (__attribute__((address_space(3))) unsigned int*)l, 16, 0, 0);
}

// ---------------- utility kernels ----------------
__global__ void zero_n(float* p, int n) {
    int i = blockIdx.x * 256 + threadIdx.x;
    if (i < n) p[i] = 0.f;
}

__global__ void invz_kernel(const float* zs, float* invz) {
    int i = threadIdx.x;
    if (i < 64) invz[i] = 1.0f / zs[i];
}

// stack theta|phi|gamma weights K-tripled [384][768]; omega -> bf16 [256][128]
__global__ void stack_params(const float* tw, const float* tb, const float* tg, const float* tbe,
                             const float* pw, const float* pb, const float* pg, const float* pbe,
                             const float* gw, const float* gb, const float* gg, const float* gbe,
                             const float* ow,
                             unsigned short* Wsp, float* vecs, unsigned short* omB) {
    int i = blockIdx.x * 256 + threadIdx.x;
    if (i < 98304) {
        int o = i >> 8, c = i & 255;
        float v = (o < 128) ? tw[o * 256 + c] : (o < 256) ? pw[(o - 128) * 256 + c]
                                                          : gw[(o - 256) * 256 + c];
        unsigned short hi = f2bf(v);
        unsigned short lo = f2bf(v - bf2f(hi));
        Wsp[(long)o * 768 + c] = hi;
        Wsp[(long)o * 768 + 256 + c] = lo;
        Wsp[(long)o * 768 + 512 + c] = hi;
    }
    if (i < 32768) omB[i] = f2bf(ow[i]);
    if (i < 384) {
        float b  = (i < 128) ? tb[i]  : (i < 256) ? pb[i - 128]  : gb[i - 256];
        float g  = (i < 128) ? tg[i]  : (i < 256) ? pg[i - 128]  : gg[i - 256];
        float be = (i < 128) ? tbe[i] : (i < 256) ? pbe[i - 128] : gbe[i - 256];
        vecs[i] = b; vecs[384 + i] = g; vecs[768 + i] = be;
    }
}

// x [64][256][1024] f32 -> xs [64][1024][512] bf16 rows [xh | xl]
__global__ __launch_bounds__(256) void transpose_x(const float* __restrict__ x,
                                                   unsigned short* __restrict__ xs) {
    __shared__ float t[64][68];
    const int b = blockIdx.z, c0 = blockIdx.y * 64, n0 = blockIdx.x * 64;
    const int tid = threadIdx.x;
#pragma unroll
    for (int p = 0; p < 4; ++p) {
        int i = tid + p * 256;
        int c = i >> 4, n4 = (i & 15) << 2;
        f32x4 v = *(const f32x4*)&x[((long)b * 256 + c0 + c) * 1024 + n0 + n4];
        *(f32x4*)&t[c][n4] = v;
    }
    __syncthreads();
#pragma unroll
    for (int p = 0; p < 4; ++p) {
        int i = tid + p * 256;
        int n = i >> 4, c4 = (i & 15) << 2;
        u16x4 h, l;
#pragma unroll
        for (int j = 0; j < 4; ++j) {
            float v = t[c4 + j][n];
            unsigned short hh = f2bf(v);
            h[j] = hh;
            l[j] = f2bf(v - bf2f(hh));
        }
        long o = ((long)b * 1024 + n0 + n) * 512 + c0 + c4;
        *(u16x4*)&xs[o] = h;
        *(u16x4*)&xs[o + 256] = l;
    }
}

// ================= 8-phase GEMM: BM=256, BN=128, BK=64, 8 waves =================
template <int NT, bool OUT_BF16, bool HAS_RBIAS, bool HAS_CBIAS, bool HAS_SCALE,
          bool CSTAT, bool EXPZ>
__global__ __launch_bounds__(512) void mgemm8(
    int gx, int gy,
    const unsigned short* __restrict__ A, long aBatch, long aOff, int lda,
    int athr, int adlo, int adhi,
    const unsigned short* __restrict__ B, long bBatch, long bOff, int ldb,
    int bthr, int bdlo, int bdhi,
    void* __restrict__ Cq, long cBatch, int ldc,
    const float* __restrict__ bias, const float* __restrict__ bscale,
    float* __restrict__ stats, int statStride, float* __restrict__ zsum) {
    constexpr int AU = 256 * 64;   // u16 (32 KB)
    constexpr int BU = 128 * 64;   // u16 (16 KB)
    constexpr int BUFU = AU + BU;  // 48 KB
    __shared__ unsigned short lds[3 * BUFU];   // 144 KB ring; reused by epilogue

    const int nwg = gridDim.x, bid = blockIdx.x;
    const int wk = ((bid & 7) * (nwg >> 3)) + (bid >> 3);   // nwg % 8 == 0
    const int bx = wk % gx;
    const int byz = wk / gx;
    const int by = byz % gy;
    const int z = byz / gy;

    const int tid = threadIdx.x;
    const int wave = tid >> 6, lane = tid & 63;
    const int wm = wave >> 1, wn = wave & 1;            // 4 x 2 wave grid
    const int lr = lane & 15, lg = lane >> 4;
    const int m0 = by * 256, n0 = bx * 128;
    const long aB = aOff + (long)z * aBatch;
    const long bB = bOff + (long)z * bBatch;
    const int grow = lane >> 3, gq = lane & 7;          // staging lane split

    f32x4 acc[4][4];
#pragma unroll
    for (int i = 0; i < 4; ++i)
#pragma unroll
        for (int j = 0; j < 4; ++j) acc[i][j] = (f32x4){0.f, 0.f, 0.f, 0.f};

    auto stageA = [&](int buf, int kt, int t) {
        const int ka = (kt < athr ? kt + adlo : kt + adhi);
        int seg = wave + t * 8;                 // 32 segs of 8 rows (1 KB each)
        int row = seg * 8 + grow;
        glds16(A + aB + (long)(m0 + row) * lda + ka + ((gq ^ (row & 7)) << 3),
               &lds[buf + seg * 512]);
    };
    auto stageB = [&](int buf, int kt, int t) {
        const int kb = (kt < bthr ? kt + bdlo : kt + bdhi);
        int seg = wave + t * 8;                 // 16 segs
        int row = seg * 8 + grow;
        glds16(B + bB + (long)(n0 + row) * ldb + kb + ((gq ^ (row & 7)) << 3),
               &lds[buf + AU + seg * 512]);
    };
    auto stage_all = [&](int buf, int kt) {
#pragma unroll
        for (int t = 0; t < 4; ++t) stageA(buf, kt, t);
#pragma unroll
        for (int t = 0; t < 2; ++t) stageB(buf, kt, t);
    };

    stage_all(0, 0);
    if (NT > 1) stage_all(BUFU, 64);

#pragma unroll
    for (int t = 0; t < NT; ++t) {
        const unsigned bb = (unsigned)(((t % 3) * BUFU) * 2);   // byte base
        if (t + 1 < NT) asm volatile("s_waitcnt vmcnt(6)" ::: "memory");
        else            asm volatile("s_waitcnt vmcnt(0)" ::: "memory");
        asm volatile("s_barrier" ::: "memory");   // tile t resident for all waves
        const int sbuf = ((t + 2) % 3) * BUFU;
        const int skt = (t + 2) * 64;
#pragma unroll
        for (int p = 0; p < 2; ++p) {
            i32x4 a4[4], b4[4];
#pragma unroll
            for (int mi = 0; mi < 4; ++mi) {
                unsigned r = (unsigned)(wm * 64 + mi * 16 + lr);
                unsigned ad = bb + r * 128 + ((unsigned)(((p << 2) | lg) ^ (r & 7)) << 4);
                asm volatile("ds_read_b128 %0, %1" : "=v"(a4[mi]) : "v"(ad));
            }
#pragma unroll
            for (int ni = 0; ni < 4; ++ni) {
                unsigned r = (unsigned)(wn * 64 + ni * 16 + lr);
                unsigned ad = bb + (unsigned)(AU * 2) + r * 128 +
                              ((unsigned)(((p << 2) | lg) ^ (r & 7)) << 4);
                asm volatile("ds_read_b128 %0, %1" : "=v"(b4[ni]) : "v"(ad));
            }
            if (t + 2 < NT) {           // half of tile t+2's staging per phase
                if (p == 0) { stageA(sbuf, skt, 0); stageA(sbuf, skt, 1); stageA(sbuf, skt, 2); }
                else        { stageA(sbuf, skt, 3); stageB(sbuf, skt, 0); stageB(sbuf, skt, 1); }
            }
            asm volatile("s_waitcnt lgkmcnt(0)" ::: "memory");
            __builtin_amdgcn_sched_barrier(0);
            __builtin_amdgcn_s_setprio(1);
#pragma unroll
            for (int ni = 0; ni < 4; ++ni) {
                short8 bh = __builtin_bit_cast(short8, b4[ni]);
#pragma unroll
                for (int mi = 0; mi < 4; ++mi)
                    acc[mi][ni] = __builtin_amdgcn_mfma_f32_16x16x32_bf16(
                        __builtin_bit_cast(short8, a4[mi]), bh, acc[mi][ni], 0, 0, 0);
            }
            __builtin_amdgcn_s_setprio(0);
            if (p == 0) asm volatile("s_barrier" ::: "memory");
        }
    }

    // ---- transform: acc = acc*scale + row_bias + col_bias ----
    const float sc = HAS_SCALE ? bscale[z] : 1.0f;
#pragma unroll
    for (int mi = 0; mi < 4; ++mi) {
        const int mrow = m0 + wm * 64 + mi * 16 + lg * 4;
        f32x4 rb = (f32x4){0.f, 0.f, 0.f, 0.f};
        if constexpr (HAS_RBIAS) rb = *(const f32x4*)&bias[mrow];
#pragma unroll
        for (int ni = 0; ni < 4; ++ni) {
            float cbv = HAS_CBIAS ? bias[n0 + wn * 64 + ni * 16 + lr] : 0.0f;
            acc[mi][ni] = acc[mi][ni] * sc + rb + (f32x4){cbv, cbv, cbv, cbv};
        }
    }
    if constexpr (CSTAT) {
#pragma unroll
        for (int ni = 0; ni < 4; ++ni) {
            float a = 0.f, b2 = 0.f;
#pragma unroll
            for (int mi = 0; mi < 4; ++mi) {
                f32x4 v = acc[mi][ni];
                a += v[0] + v[1] + v[2] + v[3];
                b2 += v[0] * v[0] + v[1] * v[1] + v[2] * v[2] + v[3] * v[3];
            }
            a += __shfl_xor(a, 16); a += __shfl_xor(a, 32);
            b2 += __shfl_xor(b2, 16); b2 += __shfl_xor(b2, 32);
            if (lg == 0) {
                const int col = n0 + wn * 64 + ni * 16 + lr;
                atomicAdd(&stats[col], a);
                atomicAdd(&stats[statStride + col], b2);
            }
        }
    }

    if constexpr (OUT_BF16) {
        __syncthreads();
        unsigned short* tileH = lds;          // [256][128] bf16 = 64 KB
        float zacc = 0.f;
#pragma unroll
        for (int mi = 0; mi < 4; ++mi) {
            const int lrow = wm * 64 + mi * 16 + lg * 4;
#pragma unroll
            for (int ni = 0; ni < 4; ++ni) {
                const int cl = wn * 64 + ni * 16 + lr;
                f32x4 v = acc[mi][ni];
#pragma unroll
                for (int j = 0; j < 4; ++j) {
                    unsigned short o;
                    if constexpr (EXPZ) {
                        float e = exp2f((v[j] - CEXP) * LOG2E);
                        o = f2bf(e);
                        zacc += bf2f(o);
                    } else {
                        o = f2bf(v[j]);
                    }
                    tileH[(lrow + j) * 128 + cl] = o;
                }
            }
        }
        __syncthreads();
#pragma unroll
        for (int i = tid; i < 256 * 128 / 8; i += 512) {
            int row = i >> 4, c8 = (i & 15) << 3;
            u16x8 vv = *(const u16x8*)&tileH[row * 128 + c8];
            *(u16x8*)&((unsigned short*)Cq)[(long)z * cBatch + (long)(m0 + row) * ldc + n0 + c8] = vv;
        }
        if constexpr (EXPZ) {
            __syncthreads();
            float* red = (float*)lds;
            red[tid] = zacc;
            __syncthreads();
            for (int o = 256; o > 0; o >>= 1) {
                if (tid < o) red[tid] += red[tid + o];
                __syncthreads();
            }
            if (tid == 0) atomicAdd(&zsum[z], red[0]);
        }
    } else {
        // f32 output in two 128-row passes (64 KB tile each)
        float* tileF = (float*)lds;
#pragma unroll
        for (int pass = 0; pass < 2; ++pass) {
            __syncthreads();
            if ((wm >> 1) == pass) {
#pragma unroll
                for (int mi = 0; mi < 4; ++mi) {
                    const int lrow = (wm & 1) * 64 + mi * 16 + lg * 4;
#pragma unroll
                    for (int ni = 0; ni < 4; ++ni) {
                        const int cl = wn * 64 + ni * 16 + lr;
#pragma unroll
                        for (int j = 0; j < 4; ++j) tileF[(lrow + j) * 128 + cl] = acc[mi][ni][j];
                    }
                }
            }
            __syncthreads();
#pragma unroll
            for (int i = tid; i < 128 * 128 / 4; i += 512) {
                int row = i >> 5, c4 = (i & 31) << 2;
                f32x4 vv = *(const f32x4*)&tileF[row * 128 + c4];
                *(f32x4*)&((float*)Cq)[(long)z * cBatch +
                                       (long)(m0 + pass * 128 + row) * ldc + n0 + c4] = vv;
            }
        }
    }
}

// ------- 2-phase mgemm (128 x NF*32), depth-4 ring — K7 (bf16+scale) / K8 (f32) -------
template <int NF, int KTOT, bool OUT_BF16, bool HAS_SCALE, bool HAS_RBIAS, bool HAS_CBIAS,
          bool RSTAT, bool CSTAT>
__global__ __launch_bounds__(256) void mgemm(
    int gx, int gy,
    const unsigned short* __restrict__ A, long aBatch, long aOff, int lda,
    const unsigned short* __restrict__ B, long bBatch, long bOff, int ldb,
    void* __restrict__ Cq, long cBatch, int ldc,
    const float* __restrict__ bias, const float* __restrict__ bscale,
    float* __restrict__ stats, int statStride) {
    constexpr int AU = 128 * 32;
    constexpr int BU = NF * 32 * 32;
    constexpr int BUFU = AU + BU;
    constexpr int S = KTOT / 32;
    constexpr int LPS = 2 + NF / 2;
    constexpr int COLS = NF * 32;
    __shared__ unsigned short lds[4 * BUFU];

    const int nwg = gridDim.x;
    const int bid = blockIdx.x;
    const int wk = ((bid & 7) * (nwg >> 3)) + (bid >> 3);
    const int bx = wk % gx;
    const int byz = wk / gx;
    const int by = byz % gy;
    const int z = byz / gy;

    const int tid = threadIdx.x;
    const int wave = tid >> 6, lane = tid & 63;
    const int wm = wave >> 1, wn = wave & 1;
    const int lr = lane & 15, lg = lane >> 4;
    const int m0 = by * 128, n0 = bx * COLS;
    const long aB = aOff + (long)z * aBatch;
    const long bB = bOff + (long)z * bBatch;
    const int srow = lane >> 2;
    const int sq   = lane & 3;

    f32x4 acc[4][NF];
#pragma unroll
    for (int i = 0; i < 4; ++i)
#pragma unroll
        for (int j = 0; j < NF; ++j) acc[i][j] = (f32x4){0.f, 0.f, 0.f, 0.f};

    auto stage = [&](int bufu, int kt) {
#pragma unroll
        for (int t = 0; t < 2; ++t) {
            int seg = wave + t * 4;
            int row = seg * 16 + srow;
            int gq = sq ^ ((row >> 1) & 3);
            glds16(A + aB + (long)(m0 + row) * lda + kt + gq * 8, &lds[bufu + seg * 512]);
        }
#pragma unroll
        for (int t = 0; t < NF / 2; ++t) {
            int seg = wave + t * 4;
            int row = seg * 16 + srow;
            int gq = sq ^ ((row >> 1) & 3);
            glds16(B + bB + (long)(n0 + row) * ldb + kt + gq * 8, &lds[bufu + AU + seg * 512]);
        }
    };

    stage(0, 0);
    if (S > 1) stage(BUFU, 32);
    if (S > 2) stage(2 * BUFU, 64);

#pragma unroll
    for (int s = 0; s < S; ++s) {
        const int bufu = (s & 3) * BUFU;
        const unsigned bb = (unsigned)(bufu * 2);
        const int rem = (S - 1 - s) < 2 ? (S - 1 - s) : 2;
        if (rem == 2)      asm volatile("s_waitcnt vmcnt(%0)" ::"i"(2 * LPS) : "memory");
        else if (rem == 1) asm volatile("s_waitcnt vmcnt(%0)" ::"i"(LPS) : "memory");
        else               asm volatile("s_waitcnt vmcnt(0)" ::: "memory");
        asm volatile("s_barrier" ::: "memory");
        i32x4 a4[4], b4[NF];
#pragma unroll
        for (int mi = 0; mi < 4; ++mi) {
            unsigned r = (unsigned)(wm * 64 + mi * 16 + lr);
            unsigned ad = bb + r * 64 + ((unsigned)(lg ^ ((r >> 1) & 3)) * 16);
            asm volatile("ds_read_b128 %0, %1" : "=v"(a4[mi]) : "v"(ad));
        }
#pragma unroll
        for (int ni = 0; ni < NF; ++ni) {
            unsigned r = (unsigned)(wn * NF * 16 + ni * 16 + lr);
            unsigned ad = bb + (unsigned)(AU * 2) + r * 64 + ((unsigned)(lg ^ ((r >> 1) & 3)) * 16);
            asm volatile("ds_read_b128 %0, %1" : "=v"(b4[ni]) : "v"(ad));
        }
        if (s + 3 < S) stage(((s + 3) & 3) * BUFU, (s + 3) * 32);
        asm volatile("s_waitcnt lgkmcnt(0)" ::: "memory");
        __builtin_amdgcn_sched_barrier(0);
        __builtin_amdgcn_s_setprio(1);
#pragma unroll
        for (int ni = 0; ni < NF; ++ni) {
            short8 bh = __builtin_bit_cast(short8, b4[ni]);
#pragma unroll
            for (int mi = 0; mi < 4; ++mi)
                acc[mi][ni] = __builtin_amdgcn_mfma_f32_16x16x32_bf16(
                    __builtin_bit_cast(short8, a4[mi]), bh, acc[mi][ni], 0, 0, 0);
        }
        __builtin_amdgcn_s_setprio(0);
    }

    __syncthreads();
    const float sc = HAS_SCALE ? bscale[z] : 1.0f;
    unsigned short* tileH = lds;     // [128][COLS] bf16
    float* tileF = (float*)lds;      // [128][COLS] f32
    float scol[NF], s2col[NF];
    if constexpr (CSTAT) {
#pragma unroll
        for (int ni = 0; ni < NF; ++ni) { scol[ni] = 0.f; s2col[ni] = 0.f; }
    }
#pragma unroll
    for (int mi = 0; mi < 4; ++mi) {
        const int mrow = m0 + wm * 64 + mi * 16 + lg * 4;
        const int lrow = wm * 64 + mi * 16 + lg * 4;
        f32x4 bi = (f32x4){0.f, 0.f, 0.f, 0.f};
        if constexpr (HAS_RBIAS) bi = *(const f32x4*)&bias[mrow];
        f32x4 s = (f32x4){0.f, 0.f, 0.f, 0.f}, s2 = s;
#pragma unroll
        for (int ni = 0; ni < NF; ++ni) {
            const int cl = wn * NF * 16 + ni * 16 + lr;
            f32x4 v = acc[mi][ni] * sc + bi;
            if constexpr (HAS_CBIAS) {
                float bc = bias[n0 + cl];
                v += (f32x4){bc, bc, bc, bc};
            }
            if constexpr (RSTAT) { s += v; s2 += v * v; }
            if constexpr (CSTAT) {
                scol[ni] += v[0] + v[1] + v[2] + v[3];
                s2col[ni] += v[0] * v[0] + v[1] * v[1] + v[2] * v[2] + v[3] * v[3];
            }
            if constexpr (OUT_BF16) {
#pragma unroll
                for (int j = 0; j < 4; ++j) tileH[(lrow + j) * COLS + cl] = f2bf(v[j]);
            } else {
#pragma unroll
                for (int j = 0; j < 4; ++j) tileF[(lrow + j) * COLS + cl] = v[j];
            }
        }
        if constexpr (RSTAT) {
#pragma unroll
            for (int m = 1; m < 16; m <<= 1) {
#pragma unroll
                for (int r = 0; r < 4; ++r) {
                    s[r] += __shfl_xor(s[r], m);
                    s2[r] += __shfl_xor(s2[r], m);
                }
            }
            if (lr == 0) {
#pragma unroll
                for (int r = 0; r < 4; ++r) {
                    atomicAdd(&stats[mrow + r], s[r]);
                    atomicAdd(&stats[statStride + mrow + r], s2[r]);
                }
            }
        }
    }
    if constexpr (CSTAT) {
#pragma unroll
        for (int ni = 0; ni < NF; ++ni) {
            float a = scol[ni], b2 = s2col[ni];
            a += __shfl_xor(a, 16); a += __shfl_xor(a, 32);
            b2 += __shfl_xor(b2, 16); b2 += __shfl_xor(b2, 32);
            if (lg == 0) {
                const int col = n0 + wn * NF * 16 + ni * 16 + lr;
                atomicAdd(&stats[col], a);
                atomicAdd(&stats[statStride + col], b2);
            }
        }
    }
    __syncthreads();
    if constexpr (OUT_BF16) {
#pragma unroll
        for (int i = tid; i < 128 * COLS / 8; i += 256) {
            int row = i / (COLS / 8), c8 = (i % (COLS / 8)) * 8;
            u16x8 vv = *(const u16x8*)&tileH[row * COLS + c8];
            *(u16x8*)&((unsigned short*)Cq)[(long)z * cBatch + (long)(m0 + row) * ldc + n0 + c8] = vv;
        }
    } else {
#pragma unroll
        for (int i = tid; i < 128 * COLS / 4; i += 256) {
            int row = i / (COLS / 4), c4 = (i % (COLS / 4)) * 4;
            f32x4 vv = *(const f32x4*)&tileF[row * COLS + c4];
            *(f32x4*)&((float*)Cq)[(long)z * cBatch + (long)(m0 + row) * ldc + n0 + c4] = vv;
        }
    }
}

// raw sums -> per-channel scale/shift
__global__ void finalize_stats(const float* __restrict__ raw, int n, int stride,
                               const float* __restrict__ g, const float* __restrict__ beta,
                               float* __restrict__ osc, float* __restrict__ osh) {
    int ch = blockIdx.x * 256 + threadIdx.x;
    if (ch < n) {
        double mean = (double)raw[ch] / 65536.0;
        double var = (double)raw[stride + ch] / 65536.0 - mean * mean;
        double s = (double)g[ch] / sqrt(var + 1e-5);
        osc[ch] = (float)s;
        osh[ch] = (float)((double)beta[ch] - mean * s);
    }
}

// normalize theta/phi cols (0..255) of YT [65536][384] -> tps rows [th|tl|ph|pl] (512)
__global__ __launch_bounds__(256) void norm_tp(const float* __restrict__ YT,
                                               const float* __restrict__ sc,
                                               const float* __restrict__ sh,
                                               unsigned short* __restrict__ tps) {
    const long total = 64L * 1024 * 64;  // f4 groups (256 cols / 4)
    for (long idx = (long)blockIdx.x * 256 + threadIdx.x; idx < total;
         idx += (long)gridDim.x * 256) {
        long row = idx >> 6;
        int cg = (int)(idx & 63) << 2;
        f32x4 v = *(const f32x4*)&YT[row * 384 + cg];
        f32x4 scv = *(const f32x4*)&sc[cg];
        f32x4 shv = *(const f32x4*)&sh[cg];
        v = v * scv + shv;
        u16x4 h, l;
#pragma unroll
        for (int j = 0; j < 4; ++j) {
            unsigned short hh = f2bf(v[j]);
            h[j] = hh;
            l[j] = f2bf(v[j] - bf2f(hh));
        }
        long rb = row * 512;
        if (cg < 128) {               // theta: th | tl
            *(u16x4*)&tps[rb + cg] = h;
            *(u16x4*)&tps[rb + 128 + cg] = l;
        } else {                      // phi: ph | pl at 256/384
            *(u16x4*)&tps[rb + 128 + cg] = h;
            *(u16x4*)&tps[rb + 256 + cg] = l;
        }
    }
}

// gamma cols (256..383) of YT [65536][384], transpose -> g bf16 [64][128][1024]
__global__ __launch_bounds__(256) void norm_g(const float* __restrict__ YT,
                                              const float* __restrict__ sc,
                                              const float* __restrict__ sh,
                                              unsigned short* __restrict__ g) {
    __shared__ float t[64][68];
    const int b = blockIdx.z, c0 = blockIdx.y * 64, n0 = blockIdx.x * 64;
    const int tid = threadIdx.x;
#pragma unroll
    for (int p = 0; p < 4; ++p) {
        int i = tid + p * 256;
        int n = i >> 4, c4 = (i & 15) << 2;
        f32x4 v = *(const f32x4*)&YT[((long)b * 1024 + n0 + n) * 384 + 256 + c0 + c4];
        f32x4 scv = *(const f32x4*)&sc[256 + c0 + c4];
        f32x4 shv = *(const f32x4*)&sh[256 + c0 + c4];
        v = v * scv + shv;
        *(f32x4*)&t[n][c4] = v;
    }
    __syncthreads();
#pragma unroll
    for (int p = 0; p < 4; ++p) {
        int i = tid + p * 256;
        int c = i >> 4, n4 = (i & 15) << 2;
        u16x4 o;
#pragma unroll
        for (int j = 0; j < 4; ++j) o[j] = f2bf(t[n4 + j][c]);
        *(u16x4*)&g[((long)b * 128 + c0 + c) * 1024 + n0 + n4] = o;
    }
}

// out[b][oc][n] = x + sc2[oc]*out0T[b][n][oc] + sh2[oc]  (LDS tile transpose)
__global__ __launch_bounds__(256) void final_kernel(const float* __restrict__ x,
                                                    const float* __restrict__ out0T,
                                                    const float* __restrict__ sc,
                                                    const float* __restrict__ sh,
                                                    float* __restrict__ out) {
    __shared__ float t[64][68];
    const int b = blockIdx.z, oc0 = blockIdx.y * 64, n0 = blockIdx.x * 64;
    const int tid = threadIdx.x;
#pragma unroll
    for (int p = 0; p < 4; ++p) {
        int i = tid + p * 256;
        int n = i >> 4, c4 = (i & 15) << 2;
        f32x4 v = *(const f32x4*)&out0T[((long)b * 1024 + n0 + n) * 256 + oc0 + c4];
        *(f32x4*)&t[n][c4] = v;
    }
    __syncthreads();
#pragma unroll
    for (int p = 0; p < 4; ++p) {
        int i = tid + p * 256;
        int oc = i >> 4, n4 = (i & 15) << 2;
        const float scv = sc[oc0 + oc], shv = sh[oc0 + oc];
        long o = ((long)b * 256 + oc0 + oc) * 1024 + n0 + n4;
        f32x4 xv = *(const f32x4*)&x[o];
        f32x4 v;
#pragma unroll
        for (int j = 0; j < 4; ++j) v[j] = xv[j] + t[n4 + j][oc] * scv + shv;
        *(f32x4*)&out[o] = v;
    }
}

extern "C" void kernel_launch(void* const* d_in, const int* in_sizes, int n_in,
                              void* d_out, int out_size, void* d_ws, size_t ws_size,
                              hipStream_t stream) {
    const float* x        = (const float*)d_in[0];
    const float* theta_w  = (const float*)d_in[1];
    const float* theta_b  = (const float*)d_in[2];
    const float* theta_g  = (const float*)d_in[3];
    const float* theta_be = (const float*)d_in[4];
    const float* phi_w    = (const float*)d_in[5];
    const float* phi_b    = (const float*)d_in[6];
    const float* phi_g    = (const float*)d_in[7];
    const float* phi_be   = (const float*)d_in[8];
    const float* gamma_w  = (const float*)d_in[9];
    const float* gamma_b  = (const float*)d_in[10];
    const float* gamma_g  = (const float*)d_in[11];
    const float* gamma_be = (const float*)d_in[12];
    const float* omega_w  = (const float*)d_in[13];
    const float* omega_b  = (const float*)d_in[14];
    const float* omega_g  = (const float*)d_in[15];
    const float* omega_be = (const float*)d_in[16];
    float* out = (float*)d_out;

    const size_t need = (size_t)WS_FLOATS * 4;
    if (ws_size < need) {
        fprintf(stderr, "kernel_launch: ws_size %zu < needed %zu\n", ws_size, need);
        return;
    }
    float* ws = (float*)d_ws;
    unsigned short* Wsp = (unsigned short*)(ws + OFF_WST);
    float* vecs = ws + OFF_VEC;
    float* r1   = ws + OFF_R1;
    float* r2   = ws + OFF_R2;
    float* zs   = ws + OFF_ZS;
    float* sc1  = ws + OFF_SC1;
    float* sh1  = ws + OFF_SH1;
    float* sc2  = ws + OFF_SC2;
    float* sh2  = ws + OFF_SH2;
    float* invz = ws + OFF_INVZ;
    unsigned short* omB = (unsigned short*)(ws + OFF_OM);   // [256][128] bf16
    unsigned short* xs  = (unsigned short*)(ws + OFF_X);    // [65536][512] hi|lo
    unsigned short* tps = (unsigned short*)(ws + OFF_X);    // same region (xs dead)
    float* out0T        = ws + OFF_X;                       // f32 [65536][256] (tps dead)
    float* YT           = ws + OFF_Y;                       // f32 [65536][384]
    unsigned short* P   = (unsigned short*)(ws + OFF_Y);    // bf16 [64][1024][1024] (YT dead)
    unsigned short* g   = (unsigned short*)(ws + OFF_C);    // [64][128][1024]
    unsigned short* satT= (unsigned short*)(ws + OFF_D);    // [65536][128]

    const int NOMAP = 1 << 30;

    zero_n<<<6, 256, 0, stream>>>(r1, 1344);
    stack_params<<<384, 256, 0, stream>>>(theta_w, theta_b, theta_g, theta_be,
                                          phi_w, phi_b, phi_g, phi_be,
                                          gamma_w, gamma_b, gamma_g, gamma_be,
                                          omega_w, Wsp, vecs, omB);
    transpose_x<<<dim3(16, 4, 64), 256, 0, stream>>>(x, xs);

    // K1 (8-phase): YT[b*1024+n][oc] = xs_trip[n][:] . Wsp[oc][:] + bias[oc]
    mgemm8<12, false, false, true, false, true, false><<<768, 512, 0, stream>>>(
        3, 256,
        xs, 0, 0, 512, 256, 0, -256,
        Wsp, 0, 0, 768, NOMAP, 0, 0,
        YT, 0, 384, vecs, nullptr, r1, 384, nullptr);
    finalize_stats<<<2, 256, 0, stream>>>(r1, 384, 384, vecs + 384, vecs + 768, sc1, sh1);

    norm_tp<<<4096, 256, 0, stream>>>(YT, sc1, sh1, tps);   // overwrites xs
    norm_g<<<dim3(16, 2, 64), 256, 0, stream>>>(YT, sc1, sh1, g);

    // K4 (8-phase): P[n][m] = exp(theta_n.phi_m - 40) bf16 + Z  (K=384 tripled)
    mgemm8<6, true, false, false, false, false, true><<<2048, 512, 0, stream>>>(
        8, 4,
        tps, 524288, 0, 512, 128, 0, -128,
        tps, 524288, 0, 512, 256, 256, 0,
        P, 1048576, 1024, nullptr, nullptr, nullptr, 0, zs);
    invz_kernel<<<1, 64, 0, stream>>>(zs, invz);

    // K7 (2-phase, 2 blocks/CU): satT[n][ch] = invz[b] * sum_m P[n][m] g[ch][m]
    // A=P rows (M=1024/z), B=g[z]; NF=4 -> full 128 cols; grid 1*8*64 = 512.
    mgemm<4, 1024, true, true, false, false, false, false><<<512, 256, 0, stream>>>(
        1, 8,
        P, 1048576, 0, 1024,
        g, 131072, 0, 1024,
        satT, 131072, 128, nullptr, invz, nullptr, 0);

    // K8 (2-phase, r17/r20-proven config): out0T[b*1024+n][oc] =
    //   satT[n][:].omB[oc][:] + omega_b[oc]; col bias + col stats.
    mgemm<4, 128, false, false, false, true, false, true><<<1024, 256, 0, stream>>>(
        2, 8,
        satT, 131072, 0, 128,
        omB, 0, 0, 128,
        out0T, 262144, 256, omega_b, nullptr, r2, 256);
    finalize_stats<<<1, 256, 0, stream>>>(r2, 256, 256, omega_g, omega_be, sc2, sh2);

    final_kernel<<<dim3(16, 4, 64), 256, 0, stream>>>(x, out0T, sc2, sh2, out);
}